// Round 6
// baseline (253.360 us; speedup 1.0000x reference)
//
#include <hip/hip_runtime.h>

#define HID 128
#define F_IN 11
#define FP 16
#define N_ACT 6
#define EPB 2048   // edges per block for hist/part kernels (= 8 * 256)
#define LMAX 6144  // k_local LDS staging capacity (edges)

typedef __bf16 bf16;
typedef __bf16 v8bf __attribute__((ext_vector_type(8)));
typedef float f32x4 __attribute__((ext_vector_type(4)));

__device__ inline float lo16(unsigned u) { return __uint_as_float(u << 16); }
__device__ inline float hi16(unsigned u) { return __uint_as_float(u & 0xffff0000u); }
__device__ inline unsigned pk2(float a, float b) {
  union { bf16 h; unsigned short u; } x, y;
  x.h = (bf16)a; y.h = (bf16)b;
  return ((unsigned)y.u << 16) | x.u;
}

// ---------------- CSR build (two-level counting sort; requires N < 65536) ----------------

__global__ __launch_bounds__(256) void k_hist(const int* __restrict__ edst,
                                              int* __restrict__ bhist, int E, int nbkt) {
  __shared__ int hist[256];
  int t = threadIdx.x;
  hist[t] = 0;
  __syncthreads();
  int start = blockIdx.x * EPB, end = min(E, start + EPB);
  for (int e = start + t; e < end; e += 256)
    atomicAdd(&hist[edst[e] >> 8], 1);
  __syncthreads();
  if (t < nbkt && hist[t]) atomicAdd(&bhist[t], hist[t]);
}

// scan bucket counts -> bucketbase; init cursors; zero gsum
__global__ __launch_bounds__(256) void k_bscan(const int* __restrict__ bhist,
                                               int* __restrict__ gcur,
                                               int* __restrict__ bucketbase,
                                               float* __restrict__ gsum,
                                               int nbkt, int E) {
  __shared__ int sh[256];
  int t = threadIdx.x;
  if (t < HID) gsum[t] = 0.f;
  int v = (t < nbkt) ? bhist[t] : 0;
  sh[t] = v;
  __syncthreads();
  for (int off = 1; off < 256; off <<= 1) {
    int x = (t >= off) ? sh[t - off] : 0;
    __syncthreads();
    sh[t] += x;
    __syncthreads();
  }
  int base = sh[t] - v;  // exclusive
  if (t < nbkt) { bucketbase[t] = base; gcur[t] = base; }
  if (t == nbkt) bucketbase[t] = E;
}

// block-local sort by bucket + bulk reservation + contiguous run writes.
__global__ __launch_bounds__(256) void k_part(const int* __restrict__ esrc,
                                              const int* __restrict__ edst,
                                              int* __restrict__ gcur,
                                              unsigned* __restrict__ ebuf,
                                              int E, int nbkt) {
  __shared__ int hist[256], lofs[256], lcur[256], gbase[256];
  __shared__ unsigned sbuf[EPB];
  int t = threadIdx.x;
  hist[t] = 0;
  __syncthreads();
  int start = blockIdx.x * EPB, end = min(E, start + EPB);
  unsigned u[8];
#pragma unroll
  for (int i = 0; i < 8; ++i) {
    int e = start + t + i * 256;
    if (e < end) {
      int s = esrc[e], d = edst[e];
      u[i] = ((unsigned)d << 16) | (unsigned)s;
      atomicAdd(&hist[d >> 8], 1);
    }
  }
  __syncthreads();
  int h = hist[t];
  lofs[t] = h;
  __syncthreads();
  for (int off = 1; off < 256; off <<= 1) {
    int x = (t >= off) ? lofs[t - off] : 0;
    __syncthreads();
    lofs[t] += x;
    __syncthreads();
  }
  lcur[t] = lofs[t] - h;
  if (t < nbkt && h) gbase[t] = atomicAdd(&gcur[t], h);
  __syncthreads();
#pragma unroll
  for (int i = 0; i < 8; ++i) {
    int e = start + t + i * 256;
    if (e < end) {
      int b = (int)(u[i] >> 24);
      int p = atomicAdd(&lcur[b], 1);
      sbuf[p] = u[i];
    }
  }
  __syncthreads();
  int m = end - start;
  for (int i = t; i < m; i += 256) {
    unsigned v = sbuf[i];
    int b = (int)(v >> 24);
    int excl = lofs[b] - hist[b];
    ebuf[gbase[b] + (i - excl)] = v;
  }
}

// one workgroup per bucket: LDS-staged local hist + scan + fill.
__global__ __launch_bounds__(256) void k_local(const unsigned* __restrict__ ebuf,
                                               const int* __restrict__ bucketbase,
                                               int* __restrict__ rowptr,
                                               float* __restrict__ dinv,
                                               unsigned short* __restrict__ cs,
                                               int n) {
  __shared__ int hist[256], lofs[256], cur[256];
  __shared__ unsigned sb[LMAX];
  int b = blockIdx.x, t = threadIdx.x;
  int rb = bucketbase[b], re = bucketbase[b + 1];
  int m = re - rb;
  int nbase = b << 8;
  bool fit = (m <= LMAX);
  hist[t] = 0;
  __syncthreads();
  if (fit) {
    for (int i = t; i < m; i += 256) {
      unsigned u = ebuf[rb + i];
      sb[i] = u;
      atomicAdd(&hist[(int)(u >> 16) - nbase], 1);
    }
  } else {
    for (int i = t; i < m; i += 256)
      atomicAdd(&hist[(int)(ebuf[rb + i] >> 16) - nbase], 1);
  }
  __syncthreads();
  int h = hist[t];
  lofs[t] = h;
  __syncthreads();
  for (int off = 1; off < 256; off <<= 1) {
    int x = (t >= off) ? lofs[t - off] : 0;
    __syncthreads();
    lofs[t] += x;
    __syncthreads();
  }
  int excl = lofs[t] - h;
  cur[t] = rb + excl;
  int g = nbase + t;
  if (g <= n) rowptr[g] = rb + excl;
  if (g < n) dinv[g] = rsqrtf((float)h + 1.0f);
  __syncthreads();
  if (fit) {
    for (int i = t; i < m; i += 256) {
      unsigned u = sb[i];
      int p = atomicAdd(&cur[(int)(u >> 16) - nbase], 1);
      cs[p] = (unsigned short)(u & 0xffffu);
    }
  } else {
    for (int i = t; i < m; i += 256) {
      unsigned u = ebuf[rb + i];
      int p = atomicAdd(&cur[(int)(u >> 16) - nbase], 1);
      cs[p] = (unsigned short)(u & 0xffffu);
    }
  }
}

// ---------------- feature prep: pad x->xs (scaled bf16) + weight transposes ----------------

__global__ __launch_bounds__(256) void k_prep(const float* __restrict__ x,
                                              const float* __restrict__ dinv,
                                              bf16* __restrict__ xs,
                                              const float* __restrict__ W2,
                                              const float* __restrict__ W3,
                                              bf16* __restrict__ WT2,
                                              bf16* __restrict__ WT3, int n) {
  int i = blockIdx.x * 256 + threadIdx.x;
  if (i < 16384) {
    int nn = i >> 7, k = i & 127;
    WT2[i] = (bf16)W2[k * 128 + nn];
    WT3[i] = (bf16)W3[k * 128 + nn];
  }
  if (i < n * FP) {
    int node = i >> 4, c = i & 15;
    float v = (c < F_IN) ? x[(size_t)node * F_IN + c] * dinv[node] : 0.f;
    xs[i] = (bf16)v;
  }
}

// ---------------- layer 1: fused gather16 + 11->128 GEMM ----------------

__global__ __launch_bounds__(256) void k_layer1(const bf16* __restrict__ xs,
                                                const float* __restrict__ dinv,
                                                const int* __restrict__ rowptr,
                                                const unsigned short* __restrict__ cs,
                                                const float* __restrict__ W1,
                                                const float* __restrict__ b1,
                                                bf16* __restrict__ hs, int n) {
  __shared__ float Ws[F_IN * HID];
  __shared__ float A1s[64][17];
  int tid = threadIdx.x;
  int n0 = blockIdx.x * 64;
  for (int i = tid; i < F_IN * HID; i += 256) Ws[i] = W1[i];
  // gather: 4 waves x 16 nodes; 8-lane groups, 2 rounds
  int wave = tid >> 6, lane = tid & 63;
  int g8 = lane >> 3, c = lane & 7;
  const unsigned* xs2 = (const unsigned*)xs;
#pragma unroll
  for (int r = 0; r < 2; ++r) {
    int row = wave * 16 + r * 8 + g8;
    int node = n0 + row;
    unsigned sv = 0;
    int j = 0, jend = 0;
    float dd = 0.f;
    if (node < n) {
      sv = xs2[(size_t)node * 8 + c];
      j = rowptr[node];
      jend = rowptr[node + 1];
      dd = dinv[node];
    }
    float ax = lo16(sv), ay = hi16(sv);
    for (; j < jend; j += 4) {
#pragma unroll
      for (int k = 0; k < 4; ++k) {
        int jj = j + k;
        bool ok = jj < jend;
        int sidx = cs[ok ? jj : jend - 1];
        unsigned v = xs2[(size_t)sidx * 8 + c];
        float mm = ok ? 1.f : 0.f;
        ax = fmaf(lo16(v), mm, ax);
        ay = fmaf(hi16(v), mm, ay);
      }
    }
    A1s[row][c * 2] = ax * dd;
    A1s[row][c * 2 + 1] = ay * dd;
  }
  __syncthreads();
  // GEMM: thread = (tr: 4 nodes, tc: 8 cols)
  int tc = tid & 15, tr = tid >> 4;
  float bb[8];
#pragma unroll
  for (int j = 0; j < 8; ++j) bb[j] = b1[tc * 8 + j];
#pragma unroll
  for (int i = 0; i < 4; ++i) {
    int row = tr * 4 + i;
    int node = n0 + row;
    if (node >= n) continue;
    float acc[8];
#pragma unroll
    for (int j = 0; j < 8; ++j) acc[j] = 0.f;
#pragma unroll
    for (int k = 0; k < F_IN; ++k) {
      float xk = A1s[row][k];
      const float* wr = &Ws[k * HID + tc * 8];
#pragma unroll
      for (int j = 0; j < 8; ++j) acc[j] = fmaf(xk, wr[j], acc[j]);
    }
    float dd = dinv[node];
    uint4 o;
    o.x = pk2(fmaxf(acc[0] + bb[0], 0.f) * dd, fmaxf(acc[1] + bb[1], 0.f) * dd);
    o.y = pk2(fmaxf(acc[2] + bb[2], 0.f) * dd, fmaxf(acc[3] + bb[3], 0.f) * dd);
    o.z = pk2(fmaxf(acc[4] + bb[4], 0.f) * dd, fmaxf(acc[5] + bb[5], 0.f) * dd);
    o.w = pk2(fmaxf(acc[6] + bb[6], 0.f) * dd, fmaxf(acc[7] + bb[7], 0.f) * dd);
    *(uint4*)(hs + (size_t)node * HID + tc * 8) = o;
  }
}

// ---------------- layers 2/3: fused gather128 + MFMA GEMM ----------------

// Gathers 64 nodes' aggregated rows into swizzled LDS A-tile, then MFMA with WT.
// FINAL=false: writes H2 = relu(acc+b)*dinv.  FINAL=true: column-sums relu(acc+b) into gsum.
template <bool FINAL>
__global__ __launch_bounds__(256) void k_layer(const bf16* __restrict__ hs,
                                               const float* __restrict__ dinv,
                                               const int* __restrict__ rowptr,
                                               const unsigned short* __restrict__ cs,
                                               const bf16* __restrict__ WT,
                                               const float* __restrict__ b,
                                               bf16* __restrict__ H2,
                                               float* __restrict__ gsum, int n) {
  __shared__ bf16 Asm[64 * 128];
  __shared__ bf16 Wsm[128 * 128];
  __shared__ float colacc[128];
  int tid = threadIdx.x;
  int n0 = blockIdx.x * 64;
  if (FINAL && tid < 128) colacc[tid] = 0.f;
  // stage WT (swizzled)
  {
    const float4* Wg = (const float4*)WT;
    float4* Ws4 = (float4*)Wsm;
#pragma unroll
    for (int it = 0; it < 8; ++it) {
      int i = tid + it * 256;
      int row = i >> 4, kc = i & 15;
      Ws4[row * 16 + (kc ^ (row & 7))] = Wg[i];
    }
  }
  // gather: one wave per node, 16 nodes per wave; 8-deep edge unroll
  int wave = tid >> 6, lane = tid & 63;
  unsigned* Au = (unsigned*)Asm;
  const unsigned* h2 = (const unsigned*)hs;
  int kcs = lane >> 2, sub = lane & 3;
  for (int i = 0; i < 16; ++i) {
    int row = wave * 16 + i;
    int node = n0 + row;
    unsigned sv = 0;
    int j = 0, jend = 0;
    float dd = 0.f;
    if (node < n) {
      sv = h2[(size_t)node * 64 + lane];
      j = rowptr[node];
      jend = rowptr[node + 1];
      dd = dinv[node];
    }
    float ax = lo16(sv), ay = hi16(sv);
    for (; j < jend; j += 8) {
#pragma unroll
      for (int k = 0; k < 8; ++k) {
        int jj = j + k;
        bool ok = jj < jend;
        int sidx = cs[ok ? jj : jend - 1];
        unsigned v = h2[(size_t)sidx * 64 + lane];
        float mm = ok ? 1.f : 0.f;
        ax = fmaf(lo16(v), mm, ax);
        ay = fmaf(hi16(v), mm, ay);
      }
    }
    Au[(row * 16 + (kcs ^ (row & 7))) * 4 + sub] = pk2(ax * dd, ay * dd);
  }
  __syncthreads();
  // MFMA
  int l15 = lane & 15, g = lane >> 4;
  f32x4 acc[8];
#pragma unroll
  for (int f = 0; f < 8; ++f) acc[f] = (f32x4){0.f, 0.f, 0.f, 0.f};
  int arow = wave * 16 + l15;
  const float4* As4 = (const float4*)Asm;
  const float4* Ws4 = (const float4*)Wsm;
#pragma unroll
  for (int kk = 0; kk < 4; ++kk) {
    int kc = kk * 4 + g;
    v8bf a = *(const v8bf*)&As4[arow * 16 + (kc ^ (arow & 7))];
#pragma unroll
    for (int f = 0; f < 8; ++f) {
      int nrow = f * 16 + l15;
      v8bf bf = *(const v8bf*)&Ws4[nrow * 16 + (kc ^ (nrow & 7))];
      acc[f] = __builtin_amdgcn_mfma_f32_16x16x32_bf16(a, bf, acc[f], 0, 0, 0);
    }
  }
  int nodebase = n0 + wave * 16 + g * 4;
  if (FINAL) {
#pragma unroll
    for (int f = 0; f < 8; ++f) {
      float bias = b[f * 16 + l15];
      float sf = 0.f;
#pragma unroll
      for (int j = 0; j < 4; ++j) {
        int node = nodebase + j;
        if (node < n) sf += fmaxf(acc[f][j] + bias, 0.f);
      }
      atomicAdd(&colacc[f * 16 + l15], sf);
    }
    __syncthreads();
    if (tid < 128) atomicAdd(&gsum[tid], colacc[tid]);
  } else {
    float dv[4];
#pragma unroll
    for (int j = 0; j < 4; ++j)
      dv[j] = (nodebase + j < n) ? dinv[nodebase + j] : 1.f;
#pragma unroll
    for (int f = 0; f < 8; ++f) {
      float bias = b[f * 16 + l15];
#pragma unroll
      for (int j = 0; j < 4; ++j) {
        int node = nodebase + j;
        if (node < n) {
          float v = fmaxf(acc[f][j] + bias, 0.f) * dv[j];
          H2[(size_t)node * 128 + f * 16 + l15] = (bf16)v;
        }
      }
    }
  }
}

// ---------------- head ----------------

__global__ __launch_bounds__(128) void k_head(const float* __restrict__ gsum,
    const float* __restrict__ Wv1, const float* __restrict__ bv1,
    const float* __restrict__ Wv2, const float* __restrict__ bv2,
    const float* __restrict__ Wa1, const float* __restrict__ ba1,
    const float* __restrict__ Wa2, const float* __restrict__ ba2,
    float* __restrict__ out, int n) {
  __shared__ float gs[HID], ha[HID], red[2], advs[N_ACT], vsh;
  int t = threadIdx.x;
  gs[t] = gsum[t] * (1.0f / (float)n);
  __syncthreads();
  float av = bv1[t], aa = ba1[t];
  for (int k = 0; k < HID; ++k) {
    float gk = gs[k];
    av = fmaf(gk, Wv1[k * HID + t], av);
    aa = fmaf(gk, Wa1[k * HID + t], aa);
  }
  float hv = fmaxf(av, 0.f);
  ha[t] = fmaxf(aa, 0.f);
  float pv = hv * Wv2[t];
#pragma unroll
  for (int o = 32; o > 0; o >>= 1) pv += __shfl_down(pv, o);
  if ((t & 63) == 0) red[t >> 6] = pv;
  __syncthreads();
  if (t == 0) vsh = red[0] + red[1] + bv2[0];
  if (t < N_ACT) {
    float adv = ba2[t];
    for (int j = 0; j < HID; ++j) adv = fmaf(ha[j], Wa2[j * N_ACT + t], adv);
    advs[t] = adv;
  }
  __syncthreads();
  if (t < N_ACT) {
    float m = 0.f;
#pragma unroll
    for (int a = 0; a < N_ACT; ++a) m += advs[a];
    m *= (1.0f / N_ACT);
    out[t] = vsh + advs[t] - m;
  }
}

// ---------------- launch ----------------

extern "C" void kernel_launch(void* const* d_in, const int* in_sizes, int n_in,
                              void* d_out, int out_size, void* d_ws, size_t ws_size,
                              hipStream_t stream) {
  const float* x   = (const float*)d_in[0];
  const int*   ei  = (const int*)d_in[1];
  const float* W1  = (const float*)d_in[2];
  const float* b1  = (const float*)d_in[3];
  const float* W2  = (const float*)d_in[4];
  const float* b2  = (const float*)d_in[5];
  const float* W3  = (const float*)d_in[6];
  const float* b3  = (const float*)d_in[7];
  const float* Wv1 = (const float*)d_in[8];
  const float* bv1 = (const float*)d_in[9];
  const float* Wv2 = (const float*)d_in[10];
  const float* bv2 = (const float*)d_in[11];
  const float* Wa1 = (const float*)d_in[12];
  const float* ba1 = (const float*)d_in[13];
  const float* Wa2 = (const float*)d_in[14];
  const float* ba2 = (const float*)d_in[15];
  float* out = (float*)d_out;

  const int N = in_sizes[0] / F_IN;   // 50000 (< 65536 required for u16 packing)
  const int E = in_sizes[1] / 2;      // 800000
  const int* esrc = ei;
  const int* edst = ei + E;
  const int nbkt = (N + 255) >> 8;    // 196
  const int gE = (E + EPB - 1) / EPB;

  char* p = (char*)d_ws;
  auto alloc = [&](size_t bytes) {
    void* r = (void*)p;
    p += (bytes + 1023) & ~(size_t)1023;
    return r;
  };
  unsigned* ebuf   = (unsigned*)alloc((size_t)E * 4);
  int*   bhist     = (int*)alloc((size_t)nbkt * 4);
  int*   gcur      = (int*)alloc((size_t)nbkt * 4);
  int*   bktbase   = (int*)alloc((size_t)(nbkt + 1) * 4);
  int*   rowptr    = (int*)alloc((size_t)(N + 1) * 4);
  float* dinv      = (float*)alloc((size_t)N * 4);
  unsigned short* cs = (unsigned short*)alloc((size_t)E * 2);
  bf16*  xs        = (bf16*)alloc((size_t)N * FP * 2);
  bf16*  WT2       = (bf16*)alloc(128 * 128 * 2);
  bf16*  WT3       = (bf16*)alloc(128 * 128 * 2);
  bf16*  HB        = (bf16*)alloc((size_t)N * HID * 2);
  bf16*  HB2       = (bf16*)alloc((size_t)N * HID * 2);
  float* gsum      = (float*)alloc(HID * 4);

  hipMemsetAsync(bhist, 0, (size_t)nbkt * 4, stream);

  // CSR build
  k_hist<<<gE, 256, 0, stream>>>(edst, bhist, E, nbkt);
  k_bscan<<<1, 256, 0, stream>>>(bhist, gcur, bktbase, gsum, nbkt, E);
  k_part<<<gE, 256, 0, stream>>>(esrc, edst, gcur, ebuf, E, nbkt);
  k_local<<<nbkt, 256, 0, stream>>>(ebuf, bktbase, rowptr, dinv, cs, N);

  // feature prep (pad + both weight transposes)
  k_prep<<<(N * FP + 255) / 256, 256, 0, stream>>>(x, dinv, xs, W2, W3, WT2, WT3, N);

  // layers (fused gather + GEMM)
  int gL = (N + 63) / 64;
  k_layer1<<<gL, 256, 0, stream>>>(xs, dinv, rowptr, cs, W1, b1, HB, N);
  k_layer<false><<<gL, 256, 0, stream>>>(HB, dinv, rowptr, cs, WT2, b2, HB2, gsum, N);
  k_layer<true><<<gL, 256, 0, stream>>>(HB2, dinv, rowptr, cs, WT3, b3, (bf16*)nullptr, gsum, N);

  // head
  k_head<<<1, 128, 0, stream>>>(gsum, Wv1, bv1, Wv2, bv2, Wa1, ba1, Wa2, ba2, out, N);
}

// Round 7
// 207.446 us; speedup vs baseline: 1.2213x; 1.2213x over previous
//
#include <hip/hip_runtime.h>

#define HID 128
#define F_IN 11
#define FP 16
#define N_ACT 6
#define EPB 2048   // edges per block for hist/part kernels (= 8 * 256)

typedef __bf16 bf16;
typedef __bf16 v8bf __attribute__((ext_vector_type(8)));
typedef float f32x4 __attribute__((ext_vector_type(4)));

__device__ inline float lo16(unsigned u) { return __uint_as_float(u << 16); }
__device__ inline float hi16(unsigned u) { return __uint_as_float(u & 0xffff0000u); }
__device__ inline unsigned pk2(float a, float b) {
  union { bf16 h; unsigned short u; } x, y;
  x.h = (bf16)a; y.h = (bf16)b;
  return ((unsigned)y.u << 16) | x.u;
}

// ---------------- CSR build (two-level counting sort; requires N < 65536) ----------------

__global__ __launch_bounds__(256) void k_hist(const int* __restrict__ edst,
                                              int* __restrict__ bhist, int E, int nbkt) {
  __shared__ int hist[256];
  int t = threadIdx.x;
  hist[t] = 0;
  __syncthreads();
  int start = blockIdx.x * EPB, end = min(E, start + EPB);
  for (int e = start + t; e < end; e += 256)
    atomicAdd(&hist[edst[e] >> 8], 1);
  __syncthreads();
  if (t < nbkt && hist[t]) atomicAdd(&bhist[t], hist[t]);
}

// scan bucket counts -> bucketbase; init cursors; zero gsum
__global__ __launch_bounds__(256) void k_bscan(const int* __restrict__ bhist,
                                               int* __restrict__ gcur,
                                               int* __restrict__ bucketbase,
                                               float* __restrict__ gsum,
                                               int nbkt, int E) {
  __shared__ int sh[256];
  int t = threadIdx.x;
  if (t < HID) gsum[t] = 0.f;
  int v = (t < nbkt) ? bhist[t] : 0;
  sh[t] = v;
  __syncthreads();
  for (int off = 1; off < 256; off <<= 1) {
    int x = (t >= off) ? sh[t - off] : 0;
    __syncthreads();
    sh[t] += x;
    __syncthreads();
  }
  int base = sh[t] - v;  // exclusive
  if (t < nbkt) { bucketbase[t] = base; gcur[t] = base; }
  if (t == nbkt) bucketbase[t] = E;
}

// block-local sort by bucket + bulk reservation + contiguous run writes.
__global__ __launch_bounds__(256) void k_part(const int* __restrict__ esrc,
                                              const int* __restrict__ edst,
                                              int* __restrict__ gcur,
                                              unsigned* __restrict__ ebuf,
                                              int E, int nbkt) {
  __shared__ int hist[256], lofs[256], lcur[256], gbase[256];
  __shared__ unsigned sbuf[EPB];
  int t = threadIdx.x;
  hist[t] = 0;
  __syncthreads();
  int start = blockIdx.x * EPB, end = min(E, start + EPB);
  unsigned u[8];
#pragma unroll
  for (int i = 0; i < 8; ++i) {
    int e = start + t + i * 256;
    if (e < end) {
      int s = esrc[e], d = edst[e];
      u[i] = ((unsigned)d << 16) | (unsigned)s;
      atomicAdd(&hist[d >> 8], 1);
    }
  }
  __syncthreads();
  int h = hist[t];
  lofs[t] = h;
  __syncthreads();
  for (int off = 1; off < 256; off <<= 1) {
    int x = (t >= off) ? lofs[t - off] : 0;
    __syncthreads();
    lofs[t] += x;
    __syncthreads();
  }
  lcur[t] = lofs[t] - h;
  if (t < nbkt && h) gbase[t] = atomicAdd(&gcur[t], h);
  __syncthreads();
#pragma unroll
  for (int i = 0; i < 8; ++i) {
    int e = start + t + i * 256;
    if (e < end) {
      int b = (int)(u[i] >> 24);
      int p = atomicAdd(&lcur[b], 1);
      sbuf[p] = u[i];
    }
  }
  __syncthreads();
  int m = end - start;
  for (int i = t; i < m; i += 256) {
    unsigned v = sbuf[i];
    int b = (int)(v >> 24);
    int excl = lofs[b] - hist[b];
    ebuf[gbase[b] + (i - excl)] = v;
  }
}

// one workgroup per bucket: local hist + scan + fill. Writes rowptr, dinv, cs(ushort).
__global__ __launch_bounds__(256) void k_local(const unsigned* __restrict__ ebuf,
                                               const int* __restrict__ bucketbase,
                                               int* __restrict__ rowptr,
                                               float* __restrict__ dinv,
                                               unsigned short* __restrict__ cs,
                                               int n) {
  __shared__ int hist[256], lofs[256], cur[256];
  int b = blockIdx.x, t = threadIdx.x;
  int rb = bucketbase[b], re = bucketbase[b + 1];
  int nbase = b << 8;
  hist[t] = 0;
  __syncthreads();
  for (int e = rb + t; e < re; e += 256) {
    int dl = (int)(ebuf[e] >> 16) - nbase;
    atomicAdd(&hist[dl], 1);
  }
  __syncthreads();
  int h = hist[t];
  lofs[t] = h;
  __syncthreads();
  for (int off = 1; off < 256; off <<= 1) {
    int x = (t >= off) ? lofs[t - off] : 0;
    __syncthreads();
    lofs[t] += x;
    __syncthreads();
  }
  int excl = lofs[t] - h;
  cur[t] = rb + excl;
  int g = nbase + t;
  if (g <= n) rowptr[g] = rb + excl;
  if (g < n) dinv[g] = rsqrtf((float)h + 1.0f);
  __syncthreads();
  for (int e = rb + t; e < re; e += 256) {
    unsigned u = ebuf[e];
    int dl = (int)(u >> 16) - nbase;
    int p = atomicAdd(&cur[dl], 1);
    cs[p] = (unsigned short)(u & 0xffffu);
  }
}

// ---------------- feature prep: pad x->xs (scaled bf16) + weight transposes ----------------

__global__ __launch_bounds__(256) void k_prep(const float* __restrict__ x,
                                              const float* __restrict__ dinv,
                                              bf16* __restrict__ xs,
                                              const float* __restrict__ W2,
                                              const float* __restrict__ W3,
                                              bf16* __restrict__ WT2,
                                              bf16* __restrict__ WT3, int n) {
  int i = blockIdx.x * 256 + threadIdx.x;
  if (i < 16384) {
    int nn = i >> 7, k = i & 127;
    WT2[i] = (bf16)W2[k * 128 + nn];
    WT3[i] = (bf16)W3[k * 128 + nn];
  }
  if (i < n * FP) {
    int node = i >> 4, c = i & 15;
    float v = (c < F_IN) ? x[(size_t)node * F_IN + c] * dinv[node] : 0.f;
    xs[i] = (bf16)v;
  }
}

// ---------------- gathers ----------------

// A1[d] = dinv[d] * (xs[d] + sum xs[src])   [n][16] bf16
__global__ __launch_bounds__(256) void k_gather16(const bf16* __restrict__ xs,
                                                  const float* __restrict__ dinv,
                                                  const int* __restrict__ rowptr,
                                                  const unsigned short* __restrict__ cs,
                                                  bf16* __restrict__ A, int n) {
  int t = threadIdx.x;
  int node = blockIdx.x * 16 + (t >> 4);
  int c = t & 15;
  if (node >= n) return;
  float acc = (float)xs[(size_t)node * FP + c];
  int j = rowptr[node], jend = rowptr[node + 1];
  for (; j + 1 < jend; j += 2) {
    int s0 = cs[j], s1 = cs[j + 1];
    acc += (float)xs[(size_t)s0 * FP + c];
    acc += (float)xs[(size_t)s1 * FP + c];
  }
  if (j < jend) acc += (float)xs[(size_t)cs[j] * FP + c];
  A[(size_t)node * FP + c] = (bf16)(acc * dinv[node]);
}

// Sliced gather: A[d][slice] = dinv[d]*(hs[d][slice] + sum hs[src][slice]),
// slice = 64B (32 bf16 cols) = blockIdx.y. Per-slice gather table is 3.2MB -> L2-resident.
// Dispatch order (x fastest) serializes slices temporally. 16 nodes/block, 16 lanes/node.
__global__ __launch_bounds__(256) void k_gather128s(const bf16* __restrict__ hs,
                                                    const float* __restrict__ dinv,
                                                    const int* __restrict__ rowptr,
                                                    const unsigned short* __restrict__ cs,
                                                    bf16* __restrict__ A, int n) {
  int t = threadIdx.x;
  int node = blockIdx.x * 16 + (t >> 4);
  int c = t & 15;                 // u32 lane within 64B slice
  int soff = blockIdx.y * 16;     // slice offset in u32 units (16 u32 = 64B)
  if (node >= n) return;
  const unsigned* h2 = (const unsigned*)hs;   // row stride 64 u32
  unsigned sv = h2[(size_t)node * 64 + soff + c];
  float ax = lo16(sv), ay = hi16(sv);
  int j = rowptr[node], jend = rowptr[node + 1];
  for (; j < jend; j += 8) {
#pragma unroll
    for (int k = 0; k < 8; ++k) {
      int jj = j + k;
      bool ok = jj < jend;
      int sidx = cs[ok ? jj : jend - 1];
      unsigned v = h2[(size_t)sidx * 64 + soff + c];
      float mm = ok ? 1.f : 0.f;
      ax = fmaf(lo16(v), mm, ax);
      ay = fmaf(hi16(v), mm, ay);
    }
  }
  float dd = dinv[node];
  ((unsigned*)A)[(size_t)node * 64 + soff + c] = pk2(ax * dd, ay * dd);
}

// ---------------- GEMMs ----------------

// A1[n,16(11 used)] @ W1[11,128] -> relu(+b)*dinv -> hs [n][128] bf16
__global__ __launch_bounds__(256) void k_gemm_in(const bf16* __restrict__ A1,
                                                 const float* __restrict__ W1,
                                                 const float* __restrict__ b1,
                                                 const float* __restrict__ dinv,
                                                 bf16* __restrict__ hs, int n) {
  __shared__ float Ws[F_IN * HID];
  int tid = threadIdx.x;
  for (int i = tid; i < F_IN * HID; i += 256) Ws[i] = W1[i];
  __syncthreads();
  int node = blockIdx.x * 16 + (tid >> 4);
  int cg = tid & 15;
  if (node >= n) return;
  float xr[F_IN];
#pragma unroll
  for (int k = 0; k < F_IN; ++k) xr[k] = (float)A1[(size_t)node * FP + k];
  float acc[8];
#pragma unroll
  for (int j = 0; j < 8; ++j) acc[j] = 0.f;
#pragma unroll
  for (int k = 0; k < F_IN; ++k) {
    const float* wr = &Ws[k * HID + cg * 8];
#pragma unroll
    for (int j = 0; j < 8; ++j) acc[j] = fmaf(xr[k], wr[j], acc[j]);
  }
  float dd = dinv[node];
  bf16* op = hs + (size_t)node * HID + cg * 8;
#pragma unroll
  for (int j = 0; j < 8; ++j)
    op[j] = (bf16)(fmaxf(acc[j] + b1[cg * 8 + j], 0.f) * dd);
}

// A[n,128](bf16) @ WT^T (bf16) -> relu(+b)*dinv -> H bf16. 64 nodes/block, MFMA 16x16x32.
__global__ __launch_bounds__(256) void k_gemm_mfma(const bf16* __restrict__ A,
                                                   const bf16* __restrict__ WT,
                                                   const float* __restrict__ b,
                                                   const float* __restrict__ dinv,
                                                   bf16* __restrict__ H, int n) {
  __shared__ bf16 Asm[64 * 128];
  __shared__ bf16 Wsm[128 * 128];
  int tid = threadIdx.x;
  int n0 = blockIdx.x * 64;
  {
    float4* As4 = (float4*)Asm;
#pragma unroll
    for (int it = 0; it < 4; ++it) {
      int i = tid + it * 256;
      int row = i >> 4, kc = i & 15;
      float4 v = make_float4(0.f, 0.f, 0.f, 0.f);
      if (n0 + row < n) v = ((const float4*)(A + (size_t)(n0 + row) * 128))[kc];
      As4[row * 16 + (kc ^ (row & 7))] = v;
    }
    const float4* Wg = (const float4*)WT;
    float4* Ws4 = (float4*)Wsm;
#pragma unroll
    for (int it = 0; it < 8; ++it) {
      int i = tid + it * 256;
      int row = i >> 4, kc = i & 15;
      Ws4[row * 16 + (kc ^ (row & 7))] = Wg[i];
    }
  }
  __syncthreads();
  int lane = tid & 63, wave = tid >> 6;
  int l15 = lane & 15, g = lane >> 4;
  f32x4 acc[8];
#pragma unroll
  for (int f = 0; f < 8; ++f) acc[f] = (f32x4){0.f, 0.f, 0.f, 0.f};
  int arow = wave * 16 + l15;
  const float4* As4 = (const float4*)Asm;
  const float4* Ws4 = (const float4*)Wsm;
#pragma unroll
  for (int kk = 0; kk < 4; ++kk) {
    int kc = kk * 4 + g;
    v8bf a = *(const v8bf*)&As4[arow * 16 + (kc ^ (arow & 7))];
#pragma unroll
    for (int f = 0; f < 8; ++f) {
      int nrow = f * 16 + l15;
      v8bf bf = *(const v8bf*)&Ws4[nrow * 16 + (kc ^ (nrow & 7))];
      acc[f] = __builtin_amdgcn_mfma_f32_16x16x32_bf16(a, bf, acc[f], 0, 0, 0);
    }
  }
  int nodebase = n0 + wave * 16 + g * 4;
  float dv[4];
#pragma unroll
  for (int j = 0; j < 4; ++j)
    dv[j] = (nodebase + j < n) ? dinv[nodebase + j] : 1.f;
#pragma unroll
  for (int f = 0; f < 8; ++f) {
    float bias = b[f * 16 + l15];
#pragma unroll
    for (int j = 0; j < 4; ++j) {
      int node = nodebase + j;
      if (node < n) {
        float v = fmaxf(acc[f][j] + bias, 0.f) * dv[j];
        H[(size_t)node * 128 + f * 16 + l15] = (bf16)v;
      }
    }
  }
}

// Layer 3: same GEMM but no H write; fused column-sum into gsum (for mean pool).
__global__ __launch_bounds__(256) void k_gemm_mfma3(const bf16* __restrict__ A,
                                                    const bf16* __restrict__ WT,
                                                    const float* __restrict__ b,
                                                    float* __restrict__ gsum, int n) {
  __shared__ bf16 Asm[64 * 128];
  __shared__ bf16 Wsm[128 * 128];
  __shared__ float colacc[128];
  int tid = threadIdx.x;
  int n0 = blockIdx.x * 64;
  if (tid < 128) colacc[tid] = 0.f;
  {
    float4* As4 = (float4*)Asm;
#pragma unroll
    for (int it = 0; it < 4; ++it) {
      int i = tid + it * 256;
      int row = i >> 4, kc = i & 15;
      float4 v = make_float4(0.f, 0.f, 0.f, 0.f);
      if (n0 + row < n) v = ((const float4*)(A + (size_t)(n0 + row) * 128))[kc];
      As4[row * 16 + (kc ^ (row & 7))] = v;
    }
    const float4* Wg = (const float4*)WT;
    float4* Ws4 = (float4*)Wsm;
#pragma unroll
    for (int it = 0; it < 8; ++it) {
      int i = tid + it * 256;
      int row = i >> 4, kc = i & 15;
      Ws4[row * 16 + (kc ^ (row & 7))] = Wg[i];
    }
  }
  __syncthreads();
  int lane = tid & 63, wave = tid >> 6;
  int l15 = lane & 15, g = lane >> 4;
  f32x4 acc[8];
#pragma unroll
  for (int f = 0; f < 8; ++f) acc[f] = (f32x4){0.f, 0.f, 0.f, 0.f};
  int arow = wave * 16 + l15;
  const float4* As4 = (const float4*)Asm;
  const float4* Ws4 = (const float4*)Wsm;
#pragma unroll
  for (int kk = 0; kk < 4; ++kk) {
    int kc = kk * 4 + g;
    v8bf a = *(const v8bf*)&As4[arow * 16 + (kc ^ (arow & 7))];
#pragma unroll
    for (int f = 0; f < 8; ++f) {
      int nrow = f * 16 + l15;
      v8bf bf = *(const v8bf*)&Ws4[nrow * 16 + (kc ^ (nrow & 7))];
      acc[f] = __builtin_amdgcn_mfma_f32_16x16x32_bf16(a, bf, acc[f], 0, 0, 0);
    }
  }
  int nodebase = n0 + wave * 16 + g * 4;
#pragma unroll
  for (int f = 0; f < 8; ++f) {
    float bias = b[f * 16 + l15];
    float sf = 0.f;
#pragma unroll
    for (int j = 0; j < 4; ++j) {
      int node = nodebase + j;
      if (node < n) sf += fmaxf(acc[f][j] + bias, 0.f);
    }
    atomicAdd(&colacc[f * 16 + l15], sf);
  }
  __syncthreads();
  if (tid < 128) atomicAdd(&gsum[tid], colacc[tid]);
}

// ---------------- head ----------------

__global__ __launch_bounds__(128) void k_head(const float* __restrict__ gsum,
    const float* __restrict__ Wv1, const float* __restrict__ bv1,
    const float* __restrict__ Wv2, const float* __restrict__ bv2,
    const float* __restrict__ Wa1, const float* __restrict__ ba1,
    const float* __restrict__ Wa2, const float* __restrict__ ba2,
    float* __restrict__ out, int n) {
  __shared__ float gs[HID], ha[HID], red[2], advs[N_ACT], vsh;
  int t = threadIdx.x;
  gs[t] = gsum[t] * (1.0f / (float)n);
  __syncthreads();
  float av = bv1[t], aa = ba1[t];
  for (int k = 0; k < HID; ++k) {
    float gk = gs[k];
    av = fmaf(gk, Wv1[k * HID + t], av);
    aa = fmaf(gk, Wa1[k * HID + t], aa);
  }
  float hv = fmaxf(av, 0.f);
  ha[t] = fmaxf(aa, 0.f);
  float pv = hv * Wv2[t];
#pragma unroll
  for (int o = 32; o > 0; o >>= 1) pv += __shfl_down(pv, o);
  if ((t & 63) == 0) red[t >> 6] = pv;
  __syncthreads();
  if (t == 0) vsh = red[0] + red[1] + bv2[0];
  if (t < N_ACT) {
    float adv = ba2[t];
    for (int j = 0; j < HID; ++j) adv = fmaf(ha[j], Wa2[j * N_ACT + t], adv);
    advs[t] = adv;
  }
  __syncthreads();
  if (t < N_ACT) {
    float m = 0.f;
#pragma unroll
    for (int a = 0; a < N_ACT; ++a) m += advs[a];
    m *= (1.0f / N_ACT);
    out[t] = vsh + advs[t] - m;
  }
}

// ---------------- launch ----------------

extern "C" void kernel_launch(void* const* d_in, const int* in_sizes, int n_in,
                              void* d_out, int out_size, void* d_ws, size_t ws_size,
                              hipStream_t stream) {
  const float* x   = (const float*)d_in[0];
  const int*   ei  = (const int*)d_in[1];
  const float* W1  = (const float*)d_in[2];
  const float* b1  = (const float*)d_in[3];
  const float* W2  = (const float*)d_in[4];
  const float* b2  = (const float*)d_in[5];
  const float* W3  = (const float*)d_in[6];
  const float* b3  = (const float*)d_in[7];
  const float* Wv1 = (const float*)d_in[8];
  const float* bv1 = (const float*)d_in[9];
  const float* Wv2 = (const float*)d_in[10];
  const float* bv2 = (const float*)d_in[11];
  const float* Wa1 = (const float*)d_in[12];
  const float* ba1 = (const float*)d_in[13];
  const float* Wa2 = (const float*)d_in[14];
  const float* ba2 = (const float*)d_in[15];
  float* out = (float*)d_out;

  const int N = in_sizes[0] / F_IN;   // 50000 (< 65536 required for u16 packing)
  const int E = in_sizes[1] / 2;      // 800000
  const int* esrc = ei;
  const int* edst = ei + E;
  const int nbkt = (N + 255) >> 8;    // 196
  const int gE = (E + EPB - 1) / EPB;

  char* p = (char*)d_ws;
  auto alloc = [&](size_t bytes) {
    void* r = (void*)p;
    p += (bytes + 1023) & ~(size_t)1023;
    return r;
  };
  unsigned* ebuf   = (unsigned*)alloc((size_t)E * 4);
  int*   bhist     = (int*)alloc((size_t)nbkt * 4);
  int*   gcur      = (int*)alloc((size_t)nbkt * 4);
  int*   bktbase   = (int*)alloc((size_t)(nbkt + 1) * 4);
  int*   rowptr    = (int*)alloc((size_t)(N + 1) * 4);
  float* dinv      = (float*)alloc((size_t)N * 4);
  unsigned short* cs = (unsigned short*)alloc((size_t)E * 2);
  bf16*  xs        = (bf16*)alloc((size_t)N * FP * 2);
  bf16*  A1        = (bf16*)alloc((size_t)N * FP * 2);
  bf16*  WT2       = (bf16*)alloc(128 * 128 * 2);
  bf16*  WT3       = (bf16*)alloc(128 * 128 * 2);
  bf16*  HB        = (bf16*)alloc((size_t)N * HID * 2);
  bf16*  AB        = (bf16*)alloc((size_t)N * HID * 2);
  float* gsum      = (float*)alloc(HID * 4);

  hipMemsetAsync(bhist, 0, (size_t)nbkt * 4, stream);

  // CSR build
  k_hist<<<gE, 256, 0, stream>>>(edst, bhist, E, nbkt);
  k_bscan<<<1, 256, 0, stream>>>(bhist, gcur, bktbase, gsum, nbkt, E);
  k_part<<<gE, 256, 0, stream>>>(esrc, edst, gcur, ebuf, E, nbkt);
  k_local<<<nbkt, 256, 0, stream>>>(ebuf, bktbase, rowptr, dinv, cs, N);

  // feature prep (pad + both weight transposes)
  k_prep<<<(N * FP + 255) / 256, 256, 0, stream>>>(x, dinv, xs, W2, W3, WT2, WT3, N);

  // layer 1
  k_gather16<<<(N + 15) / 16, 256, 0, stream>>>(xs, dinv, rowptr, cs, A1, N);
  k_gemm_in<<<(N + 15) / 16, 256, 0, stream>>>(A1, W1, b1, dinv, HB, N);

  // layer 2 (sliced gather: y = 64B feature slice, dispatched slice-major)
  dim3 gG((N + 15) / 16, 4);
  k_gather128s<<<gG, 256, 0, stream>>>(HB, dinv, rowptr, cs, AB, N);
  k_gemm_mfma<<<(N + 63) / 64, 256, 0, stream>>>(AB, WT2, b2, dinv, HB, N);

  // layer 3 (GEMM + fused column-sum; no H write)
  k_gather128s<<<gG, 256, 0, stream>>>(HB, dinv, rowptr, cs, AB, N);
  k_gemm_mfma3<<<(N + 63) / 64, 256, 0, stream>>>(AB, WT3, b3, gsum, N);

  // head
  k_head<<<1, 128, 0, stream>>>(gsum, Wv1, bv1, Wv2, bv2, Wa1, ba1, Wa2, ba2, out, N);
}

// Round 8
// 200.511 us; speedup vs baseline: 1.2636x; 1.0346x over previous
//
#include <hip/hip_runtime.h>

#define HID 128
#define F_IN 11
#define FP 16
#define N_ACT 6
#define EPB 2048   // edges per block for hist/part kernels (= 8 * 256)
#define LMAX 6144  // k_local LDS staging capacity (edges)

typedef __bf16 bf16;
typedef __bf16 v8bf __attribute__((ext_vector_type(8)));
typedef float f32x4 __attribute__((ext_vector_type(4)));

__device__ inline float lo16(unsigned u) { return __uint_as_float(u << 16); }
__device__ inline float hi16(unsigned u) { return __uint_as_float(u & 0xffff0000u); }
__device__ inline unsigned pk2(float a, float b) {
  union { bf16 h; unsigned short u; } x, y;
  x.h = (bf16)a; y.h = (bf16)b;
  return ((unsigned)y.u << 16) | x.u;
}

// ---------------- CSR build (two-level counting sort; requires N < 65536) ----------------

// bucket histogram (bucket = dst>>8) + piggybacked weight transposes (blocks 0..63)
__global__ __launch_bounds__(256) void k_hist(const int* __restrict__ edst,
                                              int* __restrict__ bhist, int E, int nbkt,
                                              const float* __restrict__ W2,
                                              const float* __restrict__ W3,
                                              bf16* __restrict__ WT2,
                                              bf16* __restrict__ WT3) {
  __shared__ int hist[256];
  int t = threadIdx.x;
  hist[t] = 0;
  __syncthreads();
  int start = blockIdx.x * EPB, end = min(E, start + EPB);
  for (int e = start + t; e < end; e += 256)
    atomicAdd(&hist[edst[e] >> 8], 1);
  if (blockIdx.x < 64) {   // WT[n][k] = bf16(W[k][n])
    int i = blockIdx.x * 256 + t;
    int nn = i >> 7, k = i & 127;
    WT2[i] = (bf16)W2[k * 128 + nn];
    WT3[i] = (bf16)W3[k * 128 + nn];
  }
  __syncthreads();
  if (t < nbkt && hist[t]) atomicAdd(&bhist[t], hist[t]);
}

// scan bucket counts -> bucketbase; init cursors; zero gsum
__global__ __launch_bounds__(256) void k_bscan(const int* __restrict__ bhist,
                                               int* __restrict__ gcur,
                                               int* __restrict__ bucketbase,
                                               float* __restrict__ gsum,
                                               int nbkt, int E) {
  __shared__ int sh[256];
  int t = threadIdx.x;
  if (t < HID) gsum[t] = 0.f;
  int v = (t < nbkt) ? bhist[t] : 0;
  sh[t] = v;
  __syncthreads();
  for (int off = 1; off < 256; off <<= 1) {
    int x = (t >= off) ? sh[t - off] : 0;
    __syncthreads();
    sh[t] += x;
    __syncthreads();
  }
  int base = sh[t] - v;  // exclusive
  if (t < nbkt) { bucketbase[t] = base; gcur[t] = base; }
  if (t == nbkt) bucketbase[t] = E;
}

// block-local sort by bucket + bulk reservation + contiguous run writes.
__global__ __launch_bounds__(256) void k_part(const int* __restrict__ esrc,
                                              const int* __restrict__ edst,
                                              int* __restrict__ gcur,
                                              unsigned* __restrict__ ebuf,
                                              int E, int nbkt) {
  __shared__ int hist[256], lofs[256], lcur[256], gbase[256];
  __shared__ unsigned sbuf[EPB];
  int t = threadIdx.x;
  hist[t] = 0;
  __syncthreads();
  int start = blockIdx.x * EPB, end = min(E, start + EPB);
  unsigned u[8];
#pragma unroll
  for (int i = 0; i < 8; ++i) {
    int e = start + t + i * 256;
    if (e < end) {
      int s = esrc[e], d = edst[e];
      u[i] = ((unsigned)d << 16) | (unsigned)s;
      atomicAdd(&hist[d >> 8], 1);
    }
  }
  __syncthreads();
  int h = hist[t];
  lofs[t] = h;
  __syncthreads();
  for (int off = 1; off < 256; off <<= 1) {
    int x = (t >= off) ? lofs[t - off] : 0;
    __syncthreads();
    lofs[t] += x;
    __syncthreads();
  }
  lcur[t] = lofs[t] - h;
  if (t < nbkt && h) gbase[t] = atomicAdd(&gcur[t], h);
  __syncthreads();
#pragma unroll
  for (int i = 0; i < 8; ++i) {
    int e = start + t + i * 256;
    if (e < end) {
      int b = (int)(u[i] >> 24);
      int p = atomicAdd(&lcur[b], 1);
      sbuf[p] = u[i];
    }
  }
  __syncthreads();
  int m = end - start;
  for (int i = t; i < m; i += 256) {
    unsigned v = sbuf[i];
    int b = (int)(v >> 24);
    int excl = lofs[b] - hist[b];
    ebuf[gbase[b] + (i - excl)] = v;
  }
}

// one workgroup per bucket: LDS-staged hist + scan + fill; also produces xs (scaled bf16 x).
__global__ __launch_bounds__(256) void k_local(const unsigned* __restrict__ ebuf,
                                               const int* __restrict__ bucketbase,
                                               int* __restrict__ rowptr,
                                               float* __restrict__ dinv,
                                               unsigned short* __restrict__ cs,
                                               const float* __restrict__ x,
                                               bf16* __restrict__ xs, int n) {
  __shared__ int hist[256], lofs[256], cur[256];
  __shared__ float dsh[256];
  __shared__ unsigned sb[LMAX];
  int b = blockIdx.x, t = threadIdx.x;
  int rb = bucketbase[b], re = bucketbase[b + 1];
  int m = re - rb;
  int nbase = b << 8;
  bool fit = (m <= LMAX);
  hist[t] = 0;
  __syncthreads();
  if (fit) {
    for (int i = t; i < m; i += 256) {
      unsigned u = ebuf[rb + i];
      sb[i] = u;
      atomicAdd(&hist[(int)(u >> 16) - nbase], 1);
    }
  } else {
    for (int i = t; i < m; i += 256)
      atomicAdd(&hist[(int)(ebuf[rb + i] >> 16) - nbase], 1);
  }
  __syncthreads();
  int h = hist[t];
  lofs[t] = h;
  __syncthreads();
  for (int off = 1; off < 256; off <<= 1) {
    int v = (t >= off) ? lofs[t - off] : 0;
    __syncthreads();
    lofs[t] += v;
    __syncthreads();
  }
  int excl = lofs[t] - h;
  cur[t] = rb + excl;
  float dv = rsqrtf((float)h + 1.0f);
  dsh[t] = dv;
  int g = nbase + t;
  if (g <= n) rowptr[g] = rb + excl;
  if (g < n) dinv[g] = dv;
  __syncthreads();
  if (fit) {
    for (int i = t; i < m; i += 256) {
      unsigned u = sb[i];
      int p = atomicAdd(&cur[(int)(u >> 16) - nbase], 1);
      cs[p] = (unsigned short)(u & 0xffffu);
    }
  } else {
    for (int i = t; i < m; i += 256) {
      unsigned u = ebuf[rb + i];
      int p = atomicAdd(&cur[(int)(u >> 16) - nbase], 1);
      cs[p] = (unsigned short)(u & 0xffffu);
    }
  }
  // xs = x * dinv (bf16, padded to 16 cols) for this bucket's nodes
  for (int i = t; i < 256 * FP; i += 256) {
    int node = nbase + (i >> 4), c = i & 15;
    if (node < n)
      xs[(size_t)node * FP + c] =
          (bf16)((c < F_IN) ? x[(size_t)node * F_IN + c] * dsh[i >> 4] : 0.f);
  }
}

// ---------------- layer 1: fused gather16 + 11->128 GEMM ----------------

__global__ __launch_bounds__(256) void k_layer1(const bf16* __restrict__ xs,
                                                const float* __restrict__ dinv,
                                                const int* __restrict__ rowptr,
                                                const unsigned short* __restrict__ cs,
                                                const float* __restrict__ W1,
                                                const float* __restrict__ b1,
                                                bf16* __restrict__ hs, int n) {
  __shared__ float Ws[F_IN * HID];
  __shared__ float A1s[64][17];
  int tid = threadIdx.x;
  int n0 = blockIdx.x * 64;
  for (int i = tid; i < F_IN * HID; i += 256) Ws[i] = W1[i];
  // gather: 4 waves x 16 nodes; 8-lane groups, 2 rounds
  int wave = tid >> 6, lane = tid & 63;
  int g8 = lane >> 3, c = lane & 7;
  const unsigned* xs2 = (const unsigned*)xs;
#pragma unroll
  for (int r = 0; r < 2; ++r) {
    int row = wave * 16 + r * 8 + g8;
    int node = n0 + row;
    unsigned sv = 0;
    int j = 0, jend = 0;
    float dd = 0.f;
    if (node < n) {
      sv = xs2[(size_t)node * 8 + c];
      j = rowptr[node];
      jend = rowptr[node + 1];
      dd = dinv[node];
    }
    float ax = lo16(sv), ay = hi16(sv);
    for (; j < jend; j += 4) {
#pragma unroll
      for (int k = 0; k < 4; ++k) {
        int jj = j + k;
        bool ok = jj < jend;
        int sidx = cs[ok ? jj : jend - 1];
        unsigned v = xs2[(size_t)sidx * 8 + c];
        float mm = ok ? 1.f : 0.f;
        ax = fmaf(lo16(v), mm, ax);
        ay = fmaf(hi16(v), mm, ay);
      }
    }
    A1s[row][c * 2] = ax * dd;
    A1s[row][c * 2 + 1] = ay * dd;
  }
  __syncthreads();
  // GEMM: thread = (tr: 4 nodes, tc: 8 cols)
  int tc = tid & 15, tr = tid >> 4;
  float bb[8];
#pragma unroll
  for (int j = 0; j < 8; ++j) bb[j] = b1[tc * 8 + j];
#pragma unroll
  for (int i = 0; i < 4; ++i) {
    int row = tr * 4 + i;
    int node = n0 + row;
    if (node >= n) continue;
    float acc[8];
#pragma unroll
    for (int j = 0; j < 8; ++j) acc[j] = 0.f;
#pragma unroll
    for (int k = 0; k < F_IN; ++k) {
      float xk = A1s[row][k];
      const float* wr = &Ws[k * HID + tc * 8];
#pragma unroll
      for (int j = 0; j < 8; ++j) acc[j] = fmaf(xk, wr[j], acc[j]);
    }
    float dd = dinv[node];
    uint4 o;
    o.x = pk2(fmaxf(acc[0] + bb[0], 0.f) * dd, fmaxf(acc[1] + bb[1], 0.f) * dd);
    o.y = pk2(fmaxf(acc[2] + bb[2], 0.f) * dd, fmaxf(acc[3] + bb[3], 0.f) * dd);
    o.z = pk2(fmaxf(acc[4] + bb[4], 0.f) * dd, fmaxf(acc[5] + bb[5], 0.f) * dd);
    o.w = pk2(fmaxf(acc[6] + bb[6], 0.f) * dd, fmaxf(acc[7] + bb[7], 0.f) * dd);
    *(uint4*)(hs + (size_t)node * HID + tc * 8) = o;
  }
}

// ---------------- sliced gather (1-D grid, slice-major guaranteed) ----------------

// A[d][slice] = dinv[d]*(hs[d][slice] + sum hs[src][slice]); slice = 64B (16 u32).
// slice = blockIdx.x / nbx -> all slice-0 blocks dispatch before slice-1:
// per-XCD L2 working set = 3.2MB slice table (fits 4MB).
__global__ __launch_bounds__(256) void k_gather128s(const bf16* __restrict__ hs,
                                                    const float* __restrict__ dinv,
                                                    const int* __restrict__ rowptr,
                                                    const unsigned short* __restrict__ cs,
                                                    bf16* __restrict__ A, int n, int nbx) {
  int bid = blockIdx.x;
  int slice = bid / nbx;
  int bx = bid - slice * nbx;
  int t = threadIdx.x;
  int node = bx * 16 + (t >> 4);
  int c = t & 15;
  int soff = slice * 16;
  if (node >= n) return;
  const unsigned* h2 = (const unsigned*)hs;   // row stride 64 u32
  unsigned sv = h2[(size_t)node * 64 + soff + c];
  float ax = lo16(sv), ay = hi16(sv);
  int j = rowptr[node], jend = rowptr[node + 1];
  for (; j < jend; j += 8) {
#pragma unroll
    for (int k = 0; k < 8; ++k) {
      int jj = j + k;
      bool ok = jj < jend;
      int sidx = cs[ok ? jj : jend - 1];
      unsigned v = h2[(size_t)sidx * 64 + soff + c];
      float mm = ok ? 1.f : 0.f;
      ax = fmaf(lo16(v), mm, ax);
      ay = fmaf(hi16(v), mm, ay);
    }
  }
  float dd = dinv[node];
  ((unsigned*)A)[(size_t)node * 64 + soff + c] = pk2(ax * dd, ay * dd);
}

// ---------------- MFMA GEMMs ----------------

// A[n,128](bf16) @ WT^T (bf16) -> relu(+b)*dinv -> H bf16. 64 nodes/block, MFMA 16x16x32.
__global__ __launch_bounds__(256) void k_gemm_mfma(const bf16* __restrict__ A,
                                                   const bf16* __restrict__ WT,
                                                   const float* __restrict__ b,
                                                   const float* __restrict__ dinv,
                                                   bf16* __restrict__ H, int n) {
  __shared__ bf16 Asm[64 * 128];
  __shared__ bf16 Wsm[128 * 128];
  int tid = threadIdx.x;
  int n0 = blockIdx.x * 64;
  {
    float4* As4 = (float4*)Asm;
#pragma unroll
    for (int it = 0; it < 4; ++it) {
      int i = tid + it * 256;
      int row = i >> 4, kc = i & 15;
      float4 v = make_float4(0.f, 0.f, 0.f, 0.f);
      if (n0 + row < n) v = ((const float4*)(A + (size_t)(n0 + row) * 128))[kc];
      As4[row * 16 + (kc ^ (row & 7))] = v;
    }
    const float4* Wg = (const float4*)WT;
    float4* Ws4 = (float4*)Wsm;
#pragma unroll
    for (int it = 0; it < 8; ++it) {
      int i = tid + it * 256;
      int row = i >> 4, kc = i & 15;
      Ws4[row * 16 + (kc ^ (row & 7))] = Wg[i];
    }
  }
  __syncthreads();
  int lane = tid & 63, wave = tid >> 6;
  int l15 = lane & 15, g = lane >> 4;
  f32x4 acc[8];
#pragma unroll
  for (int f = 0; f < 8; ++f) acc[f] = (f32x4){0.f, 0.f, 0.f, 0.f};
  int arow = wave * 16 + l15;
  const float4* As4 = (const float4*)Asm;
  const float4* Ws4 = (const float4*)Wsm;
#pragma unroll
  for (int kk = 0; kk < 4; ++kk) {
    int kc = kk * 4 + g;
    v8bf a = *(const v8bf*)&As4[arow * 16 + (kc ^ (arow & 7))];
#pragma unroll
    for (int f = 0; f < 8; ++f) {
      int nrow = f * 16 + l15;
      v8bf bf = *(const v8bf*)&Ws4[nrow * 16 + (kc ^ (nrow & 7))];
      acc[f] = __builtin_amdgcn_mfma_f32_16x16x32_bf16(a, bf, acc[f], 0, 0, 0);
    }
  }
  int nodebase = n0 + wave * 16 + g * 4;
  float dv[4];
#pragma unroll
  for (int j = 0; j < 4; ++j)
    dv[j] = (nodebase + j < n) ? dinv[nodebase + j] : 1.f;
#pragma unroll
  for (int f = 0; f < 8; ++f) {
    float bias = b[f * 16 + l15];
#pragma unroll
    for (int j = 0; j < 4; ++j) {
      int node = nodebase + j;
      if (node < n) {
        float v = fmaxf(acc[f][j] + bias, 0.f) * dv[j];
        H[(size_t)node * 128 + f * 16 + l15] = (bf16)v;
      }
    }
  }
}

// Layer 3: same GEMM but no H write; fused column-sum into gsum (for mean pool).
__global__ __launch_bounds__(256) void k_gemm_mfma3(const bf16* __restrict__ A,
                                                    const bf16* __restrict__ WT,
                                                    const float* __restrict__ b,
                                                    float* __restrict__ gsum, int n) {
  __shared__ bf16 Asm[64 * 128];
  __shared__ bf16 Wsm[128 * 128];
  __shared__ float colacc[128];
  int tid = threadIdx.x;
  int n0 = blockIdx.x * 64;
  if (tid < 128) colacc[tid] = 0.f;
  {
    float4* As4 = (float4*)Asm;
#pragma unroll
    for (int it = 0; it < 4; ++it) {
      int i = tid + it * 256;
      int row = i >> 4, kc = i & 15;
      float4 v = make_float4(0.f, 0.f, 0.f, 0.f);
      if (n0 + row < n) v = ((const float4*)(A + (size_t)(n0 + row) * 128))[kc];
      As4[row * 16 + (kc ^ (row & 7))] = v;
    }
    const float4* Wg = (const float4*)WT;
    float4* Ws4 = (float4*)Wsm;
#pragma unroll
    for (int it = 0; it < 8; ++it) {
      int i = tid + it * 256;
      int row = i >> 4, kc = i & 15;
      Ws4[row * 16 + (kc ^ (row & 7))] = Wg[i];
    }
  }
  __syncthreads();
  int lane = tid & 63, wave = tid >> 6;
  int l15 = lane & 15, g = lane >> 4;
  f32x4 acc[8];
#pragma unroll
  for (int f = 0; f < 8; ++f) acc[f] = (f32x4){0.f, 0.f, 0.f, 0.f};
  int arow = wave * 16 + l15;
  const float4* As4 = (const float4*)Asm;
  const float4* Ws4 = (const float4*)Wsm;
#pragma unroll
  for (int kk = 0; kk < 4; ++kk) {
    int kc = kk * 4 + g;
    v8bf a = *(const v8bf*)&As4[arow * 16 + (kc ^ (arow & 7))];
#pragma unroll
    for (int f = 0; f < 8; ++f) {
      int nrow = f * 16 + l15;
      v8bf bf = *(const v8bf*)&Ws4[nrow * 16 + (kc ^ (nrow & 7))];
      acc[f] = __builtin_amdgcn_mfma_f32_16x16x32_bf16(a, bf, acc[f], 0, 0, 0);
    }
  }
  int nodebase = n0 + wave * 16 + g * 4;
#pragma unroll
  for (int f = 0; f < 8; ++f) {
    float bias = b[f * 16 + l15];
    float sf = 0.f;
#pragma unroll
    for (int j = 0; j < 4; ++j) {
      int node = nodebase + j;
      if (node < n) sf += fmaxf(acc[f][j] + bias, 0.f);
    }
    atomicAdd(&colacc[f * 16 + l15], sf);
  }
  __syncthreads();
  if (tid < 128) atomicAdd(&gsum[tid], colacc[tid]);
}

// ---------------- head ----------------

__global__ __launch_bounds__(128) void k_head(const float* __restrict__ gsum,
    const float* __restrict__ Wv1, const float* __restrict__ bv1,
    const float* __restrict__ Wv2, const float* __restrict__ bv2,
    const float* __restrict__ Wa1, const float* __restrict__ ba1,
    const float* __restrict__ Wa2, const float* __restrict__ ba2,
    float* __restrict__ out, int n) {
  __shared__ float gs[HID], ha[HID], red[2], advs[N_ACT], vsh;
  int t = threadIdx.x;
  gs[t] = gsum[t] * (1.0f / (float)n);
  __syncthreads();
  float av = bv1[t], aa = ba1[t];
  for (int k = 0; k < HID; ++k) {
    float gk = gs[k];
    av = fmaf(gk, Wv1[k * HID + t], av);
    aa = fmaf(gk, Wa1[k * HID + t], aa);
  }
  float hv = fmaxf(av, 0.f);
  ha[t] = fmaxf(aa, 0.f);
  float pv = hv * Wv2[t];
#pragma unroll
  for (int o = 32; o > 0; o >>= 1) pv += __shfl_down(pv, o);
  if ((t & 63) == 0) red[t >> 6] = pv;
  __syncthreads();
  if (t == 0) vsh = red[0] + red[1] + bv2[0];
  if (t < N_ACT) {
    float adv = ba2[t];
    for (int j = 0; j < HID; ++j) adv = fmaf(ha[j], Wa2[j * N_ACT + t], adv);
    advs[t] = adv;
  }
  __syncthreads();
  if (t < N_ACT) {
    float m = 0.f;
#pragma unroll
    for (int a = 0; a < N_ACT; ++a) m += advs[a];
    m *= (1.0f / N_ACT);
    out[t] = vsh + advs[t] - m;
  }
}

// ---------------- launch ----------------

extern "C" void kernel_launch(void* const* d_in, const int* in_sizes, int n_in,
                              void* d_out, int out_size, void* d_ws, size_t ws_size,
                              hipStream_t stream) {
  const float* x   = (const float*)d_in[0];
  const int*   ei  = (const int*)d_in[1];
  const float* W1  = (const float*)d_in[2];
  const float* b1  = (const float*)d_in[3];
  const float* W2  = (const float*)d_in[4];
  const float* b2  = (const float*)d_in[5];
  const float* W3  = (const float*)d_in[6];
  const float* b3  = (const float*)d_in[7];
  const float* Wv1 = (const float*)d_in[8];
  const float* bv1 = (const float*)d_in[9];
  const float* Wv2 = (const float*)d_in[10];
  const float* bv2 = (const float*)d_in[11];
  const float* Wa1 = (const float*)d_in[12];
  const float* ba1 = (const float*)d_in[13];
  const float* Wa2 = (const float*)d_in[14];
  const float* ba2 = (const float*)d_in[15];
  float* out = (float*)d_out;

  const int N = in_sizes[0] / F_IN;   // 50000 (< 65536 required for u16 packing)
  const int E = in_sizes[1] / 2;      // 800000
  const int* esrc = ei;
  const int* edst = ei + E;
  const int nbkt = (N + 255) >> 8;    // 196
  const int gE = (E + EPB - 1) / EPB;

  char* p = (char*)d_ws;
  auto alloc = [&](size_t bytes) {
    void* r = (void*)p;
    p += (bytes + 1023) & ~(size_t)1023;
    return r;
  };
  unsigned* ebuf   = (unsigned*)alloc((size_t)E * 4);
  int*   bhist     = (int*)alloc((size_t)nbkt * 4);
  int*   gcur      = (int*)alloc((size_t)nbkt * 4);
  int*   bktbase   = (int*)alloc((size_t)(nbkt + 1) * 4);
  int*   rowptr    = (int*)alloc((size_t)(N + 1) * 4);
  float* dinv      = (float*)alloc((size_t)N * 4);
  unsigned short* cs = (unsigned short*)alloc((size_t)E * 2);
  bf16*  xs        = (bf16*)alloc((size_t)N * FP * 2);
  bf16*  WT2       = (bf16*)alloc(128 * 128 * 2);
  bf16*  WT3       = (bf16*)alloc(128 * 128 * 2);
  bf16*  HB        = (bf16*)alloc((size_t)N * HID * 2);
  bf16*  HB2       = (bf16*)alloc((size_t)N * HID * 2);
  bf16*  AB        = (bf16*)alloc((size_t)N * HID * 2);
  float* gsum      = (float*)alloc(HID * 4);

  hipMemsetAsync(bhist, 0, (size_t)nbkt * 4, stream);

  // CSR build (+ WT transposes, xs production folded in)
  k_hist<<<gE, 256, 0, stream>>>(edst, bhist, E, nbkt, W2, W3, WT2, WT3);
  k_bscan<<<1, 256, 0, stream>>>(bhist, gcur, bktbase, gsum, nbkt, E);
  k_part<<<gE, 256, 0, stream>>>(esrc, edst, gcur, ebuf, E, nbkt);
  k_local<<<nbkt, 256, 0, stream>>>(ebuf, bktbase, rowptr, dinv, cs, x, xs, N);

  // layer 1 (fused gather16 + GEMM)
  k_layer1<<<(N + 63) / 64, 256, 0, stream>>>(xs, dinv, rowptr, cs, W1, b1, HB, N);

  // layers 2/3 (slice-major gather, then MFMA GEMM)
  const int nbx = (N + 15) / 16;
  k_gather128s<<<nbx * 4, 256, 0, stream>>>(HB, dinv, rowptr, cs, AB, N, nbx);
  k_gemm_mfma<<<(N + 63) / 64, 256, 0, stream>>>(AB, WT2, b2, dinv, HB2, N);
  k_gather128s<<<nbx * 4, 256, 0, stream>>>(HB2, dinv, rowptr, cs, AB, N, nbx);
  k_gemm_mfma3<<<(N + 63) / 64, 256, 0, stream>>>(AB, WT3, b3, gsum, N);

  // head
  k_head<<<1, 128, 0, stream>>>(gsum, Wv1, bv1, Wv2, bv2, Wa1, ba1, Wa2, ba2, out, N);
}

// Round 10
// 157.362 us; speedup vs baseline: 1.6100x; 1.2742x over previous
//
#include <hip/hip_runtime.h>

#define HID 128
#define F_IN 11
#define FP 16
#define N_ACT 6
#define EPB 2048   // edges per block for k_part (= 8 * 256)
#define LMAX 6144  // k_local LDS staging capacity (edges)
#define CAP 8192   // padded bucket capacity (mean 4096, sigma 64 for uniform dst)

typedef __bf16 bf16;
typedef __bf16 v8bf __attribute__((ext_vector_type(8)));
typedef float f32x4 __attribute__((ext_vector_type(4)));
typedef float v2f __attribute__((ext_vector_type(2)));

__device__ inline float lo16(unsigned u) { return __uint_as_float(u << 16); }
__device__ inline float hi16(unsigned u) { return __uint_as_float(u & 0xffff0000u); }
__device__ inline unsigned pk2(float a, float b) {
  union { bf16 h; unsigned short u; } x, y;
  x.h = (bf16)a; y.h = (bf16)b;
  return ((unsigned)y.u << 16) | x.u;
}
// fp8 e4m3 (OCP) hardware converts — selector args must be literal constants
__device__ inline v2f fp8_dec_lo(unsigned v) {
  return __builtin_amdgcn_cvt_pk_f32_fp8(v, false);
}
__device__ inline v2f fp8_dec_hi(unsigned v) {
  return __builtin_amdgcn_cvt_pk_f32_fp8(v, true);
}
__device__ inline unsigned fp8_enc2_lo(float a, float b, unsigned old) {
  return __builtin_amdgcn_cvt_pk_fp8_f32(a, b, old, false);
}
__device__ inline unsigned fp8_enc2_hi(float a, float b, unsigned old) {
  return __builtin_amdgcn_cvt_pk_fp8_f32(a, b, old, true);
}
__device__ inline unsigned char fp8_enc1(float v) {
  return (unsigned char)(__builtin_amdgcn_cvt_pk_fp8_f32(v, v, 0u, false) & 0xffu);
}

// ---------------- CSR build (padded-bucket counting sort; requires N < 65536) ----------------

// init cursors to padded bucket bases + zero gsum (replaces hist/scan/memset)
__global__ __launch_bounds__(256) void k_init(int* __restrict__ gcur,
                                              float* __restrict__ gsum, int nbkt) {
  int t = threadIdx.x;
  if (t < nbkt) gcur[t] = t * CAP;
  if (t < HID) gsum[t] = 0.f;
}

// block-local sort by bucket + bulk reservation into padded regions + contiguous run writes.
// blocks 0..63 also produce the bf16 weight transposes.
__global__ __launch_bounds__(256) void k_part(const int* __restrict__ esrc,
                                              const int* __restrict__ edst,
                                              int* __restrict__ gcur,
                                              unsigned* __restrict__ ebuf,
                                              const float* __restrict__ W2,
                                              const float* __restrict__ W3,
                                              bf16* __restrict__ WT2,
                                              bf16* __restrict__ WT3,
                                              int E, int nbkt) {
  __shared__ int hist[256], lofs[256], lcur[256], gbase[256];
  __shared__ unsigned sbuf[EPB];
  int t = threadIdx.x;
  hist[t] = 0;
  if (blockIdx.x < 64) {   // WT[n][k] = bf16(W[k][n])
    int i = blockIdx.x * 256 + t;
    int nn = i >> 7, k = i & 127;
    WT2[i] = (bf16)W2[k * 128 + nn];
    WT3[i] = (bf16)W3[k * 128 + nn];
  }
  __syncthreads();
  int start = blockIdx.x * EPB, end = min(E, start + EPB);
  unsigned u[8];
#pragma unroll
  for (int i = 0; i < 8; ++i) {
    int e = start + t + i * 256;
    if (e < end) {
      int s = esrc[e], d = edst[e];
      u[i] = ((unsigned)d << 16) | (unsigned)s;
      atomicAdd(&hist[d >> 8], 1);
    }
  }
  __syncthreads();
  int h = hist[t];
  lofs[t] = h;
  __syncthreads();
  for (int off = 1; off < 256; off <<= 1) {
    int x = (t >= off) ? lofs[t - off] : 0;
    __syncthreads();
    lofs[t] += x;
    __syncthreads();
  }
  lcur[t] = lofs[t] - h;
  if (t < nbkt && h) gbase[t] = atomicAdd(&gcur[t], h);   // bulk reservation
  __syncthreads();
#pragma unroll
  for (int i = 0; i < 8; ++i) {
    int e = start + t + i * 256;
    if (e < end) {
      int b = (int)(u[i] >> 24);
      int p = atomicAdd(&lcur[b], 1);
      sbuf[p] = u[i];
    }
  }
  __syncthreads();
  int m = end - start;
  for (int i = t; i < m; i += 256) {
    unsigned v = sbuf[i];
    int b = (int)(v >> 24);
    int excl = lofs[b] - hist[b];
    ebuf[gbase[b] + (i - excl)] = v;
  }
}

// one workgroup per bucket: LDS-staged hist + scan + fill.
// Writes rbe(int2: edge run begin/end), dinv, cs(ushort), and xs (= x*dinv bf16 padded).
__global__ __launch_bounds__(256) void k_local(const unsigned* __restrict__ ebuf,
                                               const int* __restrict__ gcur,
                                               int2* __restrict__ rbe,
                                               float* __restrict__ dinv,
                                               unsigned short* __restrict__ cs,
                                               const float* __restrict__ x,
                                               bf16* __restrict__ xs, int n) {
  __shared__ int hist[256], lofs[256], cur[256];
  __shared__ float dsh[256];
  __shared__ unsigned sb[LMAX];
  int b = blockIdx.x, t = threadIdx.x;
  int rb = b * CAP, re = gcur[b];
  int m = re - rb;
  int nbase = b << 8;
  bool fit = (m <= LMAX);
  hist[t] = 0;
  __syncthreads();
  if (fit) {
    for (int i = t; i < m; i += 256) {
      unsigned u = ebuf[rb + i];
      sb[i] = u;
      atomicAdd(&hist[(int)(u >> 16) - nbase], 1);
    }
  } else {
    for (int i = t; i < m; i += 256)
      atomicAdd(&hist[(int)(ebuf[rb + i] >> 16) - nbase], 1);
  }
  __syncthreads();
  int h = hist[t];
  lofs[t] = h;
  __syncthreads();
  for (int off = 1; off < 256; off <<= 1) {
    int v = (t >= off) ? lofs[t - off] : 0;
    __syncthreads();
    lofs[t] += v;
    __syncthreads();
  }
  int excl = lofs[t] - h;
  cur[t] = rb + excl;
  float dv = rsqrtf((float)h + 1.0f);
  dsh[t] = dv;
  int g = nbase + t;
  if (g < n) {
    rbe[g] = make_int2(rb + excl, rb + lofs[t]);
    dinv[g] = dv;
  }
  __syncthreads();
  if (fit) {
    for (int i = t; i < m; i += 256) {
      unsigned u = sb[i];
      int p = atomicAdd(&cur[(int)(u >> 16) - nbase], 1);
      cs[p] = (unsigned short)(u & 0xffffu);
    }
  } else {
    for (int i = t; i < m; i += 256) {
      unsigned u = ebuf[rb + i];
      int p = atomicAdd(&cur[(int)(u >> 16) - nbase], 1);
      cs[p] = (unsigned short)(u & 0xffffu);
    }
  }
  // xs = x * dinv (bf16, padded to 16 cols) for this bucket's nodes
  for (int i = t; i < 256 * FP; i += 256) {
    int node = nbase + (i >> 4), c = i & 15;
    if (node < n)
      xs[(size_t)node * FP + c] =
          (bf16)((c < F_IN) ? x[(size_t)node * F_IN + c] * dsh[i >> 4] : 0.f);
  }
}

// ---------------- layer 1: fused gather16 + 11->128 GEMM -> h1 (fp8) ----------------

__global__ __launch_bounds__(256) void k_layer1(const bf16* __restrict__ xs,
                                                const float* __restrict__ dinv,
                                                const int2* __restrict__ rbe,
                                                const unsigned short* __restrict__ cs,
                                                const float* __restrict__ W1,
                                                const float* __restrict__ b1,
                                                unsigned* __restrict__ H8, int n) {
  __shared__ float Ws[F_IN * HID];
  __shared__ float A1s[64][17];
  int tid = threadIdx.x;
  int n0 = blockIdx.x * 64;
  for (int i = tid; i < F_IN * HID; i += 256) Ws[i] = W1[i];
  int wave = tid >> 6, lane = tid & 63;
  int g8 = lane >> 3, c = lane & 7;
  const unsigned* xs2 = (const unsigned*)xs;
#pragma unroll
  for (int r = 0; r < 2; ++r) {
    int row = wave * 16 + r * 8 + g8;
    int node = n0 + row;
    unsigned sv = 0;
    int j = 0, jend = 0;
    float dd = 0.f;
    if (node < n) {
      sv = xs2[(size_t)node * 8 + c];
      int2 be = rbe[node];
      j = be.x; jend = be.y;
      dd = dinv[node];
    }
    float ax = lo16(sv), ay = hi16(sv);
    for (; j < jend; j += 4) {
#pragma unroll
      for (int k = 0; k < 4; ++k) {
        int jj = j + k;
        bool ok = jj < jend;
        int sidx = cs[ok ? jj : jend - 1];
        unsigned v = xs2[(size_t)sidx * 8 + c];
        float mm = ok ? 1.f : 0.f;
        ax = fmaf(lo16(v), mm, ax);
        ay = fmaf(hi16(v), mm, ay);
      }
    }
    A1s[row][c * 2] = ax * dd;
    A1s[row][c * 2 + 1] = ay * dd;
  }
  __syncthreads();
  int tc = tid & 15, tr = tid >> 4;
  float bb[8];
#pragma unroll
  for (int j = 0; j < 8; ++j) bb[j] = b1[tc * 8 + j];
#pragma unroll
  for (int i = 0; i < 4; ++i) {
    int row = tr * 4 + i;
    int node = n0 + row;
    if (node >= n) continue;
    float acc[8];
#pragma unroll
    for (int j = 0; j < 8; ++j) acc[j] = 0.f;
#pragma unroll
    for (int k = 0; k < F_IN; ++k) {
      float xk = A1s[row][k];
      const float* wr = &Ws[k * HID + tc * 8];
#pragma unroll
      for (int j = 0; j < 8; ++j) acc[j] = fmaf(xk, wr[j], acc[j]);
    }
    float dd = dinv[node];
    float o[8];
#pragma unroll
    for (int j = 0; j < 8; ++j) o[j] = fmaxf(acc[j] + bb[j], 0.f) * dd;
    unsigned w0 = 0, w1 = 0;
    w0 = fp8_enc2_lo(o[0], o[1], w0);
    w0 = fp8_enc2_hi(o[2], o[3], w0);
    w1 = fp8_enc2_lo(o[4], o[5], w1);
    w1 = fp8_enc2_hi(o[6], o[7], w1);
    ((uint2*)H8)[(size_t)node * 16 + tc] = make_uint2(w0, w1);
  }
}

// ---------------- fp8 sliced gather (slice-major 1-D grid) ----------------

// A[d][slice] = dinv[d]*(h8[d][slice] + sum h8[src][slice]); slice = 64B (16 u32 = 64 fp8).
// Per-slice table 3.2MB. Output A is bf16 (MFMA input).
__global__ __launch_bounds__(256) void k_gather(const unsigned* __restrict__ tab,
                                                const float* __restrict__ dinv,
                                                const int2* __restrict__ rbe,
                                                const unsigned short* __restrict__ cs,
                                                bf16* __restrict__ A, int n, int nbx) {
  int bid = blockIdx.x;
  int slice = bid / nbx;
  int bx = bid - slice * nbx;
  int t = threadIdx.x;
  int node = bx * 16 + (t >> 4);
  int c = t & 15;                 // u32 (4 fp8) within slice
  int soff = slice * 16;
  if (node >= n) return;
  unsigned sv = tab[(size_t)node * 32 + soff + c];
  v2f slo = fp8_dec_lo(sv), shi = fp8_dec_hi(sv);
  float a0 = slo.x, a1 = slo.y, a2 = shi.x, a3 = shi.y;
  int2 be = rbe[node];
  int j = be.x, jend = be.y;
  for (; j < jend; j += 8) {
#pragma unroll
    for (int k = 0; k < 8; ++k) {
      int jj = j + k;
      bool ok = jj < jend;
      int sidx = cs[ok ? jj : jend - 1];
      unsigned v = tab[(size_t)sidx * 32 + soff + c];
      float mm = ok ? 1.f : 0.f;
      v2f lo = fp8_dec_lo(v), hi = fp8_dec_hi(v);
      a0 = fmaf(lo.x, mm, a0);
      a1 = fmaf(lo.y, mm, a1);
      a2 = fmaf(hi.x, mm, a2);
      a3 = fmaf(hi.y, mm, a3);
    }
  }
  float dd = dinv[node];
  ((uint2*)A)[(size_t)node * 32 + slice * 16 + c] =
      make_uint2(pk2(a0 * dd, a1 * dd), pk2(a2 * dd, a3 * dd));
}

// ---------------- MFMA GEMMs ----------------

// A[n,128](bf16) @ WT^T (bf16) -> relu(+b)*dinv -> H (fp8). 64 nodes/block, MFMA 16x16x32.
__global__ __launch_bounds__(256) void k_gemm_mfma(const bf16* __restrict__ A,
                                                   const bf16* __restrict__ WT,
                                                   const float* __restrict__ b,
                                                   const float* __restrict__ dinv,
                                                   unsigned char* __restrict__ H8, int n) {
  __shared__ bf16 Asm[64 * 128];
  __shared__ bf16 Wsm[128 * 128];
  int tid = threadIdx.x;
  int n0 = blockIdx.x * 64;
  {
    float4* As4 = (float4*)Asm;
#pragma unroll
    for (int it = 0; it < 4; ++it) {
      int i = tid + it * 256;
      int row = i >> 4, kc = i & 15;
      float4 v = make_float4(0.f, 0.f, 0.f, 0.f);
      if (n0 + row < n) v = ((const float4*)(A + (size_t)(n0 + row) * 128))[kc];
      As4[row * 16 + (kc ^ (row & 7))] = v;
    }
    const float4* Wg = (const float4*)WT;
    float4* Ws4 = (float4*)Wsm;
#pragma unroll
    for (int it = 0; it < 8; ++it) {
      int i = tid + it * 256;
      int row = i >> 4, kc = i & 15;
      Ws4[row * 16 + (kc ^ (row & 7))] = Wg[i];
    }
  }
  __syncthreads();
  int lane = tid & 63, wave = tid >> 6;
  int l15 = lane & 15, g = lane >> 4;
  f32x4 acc[8];
#pragma unroll
  for (int f = 0; f < 8; ++f) acc[f] = (f32x4){0.f, 0.f, 0.f, 0.f};
  int arow = wave * 16 + l15;
  const float4* As4 = (const float4*)Asm;
  const float4* Ws4 = (const float4*)Wsm;
#pragma unroll
  for (int kk = 0; kk < 4; ++kk) {
    int kc = kk * 4 + g;
    v8bf a = *(const v8bf*)&As4[arow * 16 + (kc ^ (arow & 7))];
#pragma unroll
    for (int f = 0; f < 8; ++f) {
      int nrow = f * 16 + l15;
      v8bf bf = *(const v8bf*)&Ws4[nrow * 16 + (kc ^ (nrow & 7))];
      acc[f] = __builtin_amdgcn_mfma_f32_16x16x32_bf16(a, bf, acc[f], 0, 0, 0);
    }
  }
  int nodebase = n0 + wave * 16 + g * 4;
  float dv[4];
#pragma unroll
  for (int j = 0; j < 4; ++j)
    dv[j] = (nodebase + j < n) ? dinv[nodebase + j] : 1.f;
#pragma unroll
  for (int f = 0; f < 8; ++f) {
    float bias = b[f * 16 + l15];
#pragma unroll
    for (int j = 0; j < 4; ++j) {
      int node = nodebase + j;
      if (node < n) {
        float v = fmaxf(acc[f][j] + bias, 0.f) * dv[j];
        H8[(size_t)node * 128 + f * 16 + l15] = fp8_enc1(v);
      }
    }
  }
}

// Layer 3: same GEMM but no H write; fused column-sum into gsum (for mean pool).
__global__ __launch_bounds__(256) void k_gemm_mfma3(const bf16* __restrict__ A,
                                                    const bf16* __restrict__ WT,
                                                    const float* __restrict__ b,
                                                    float* __restrict__ gsum, int n) {
  __shared__ bf16 Asm[64 * 128];
  __shared__ bf16 Wsm[128 * 128];
  __shared__ float colacc[128];
  int tid = threadIdx.x;
  int n0 = blockIdx.x * 64;
  if (tid < 128) colacc[tid] = 0.f;
  {
    float4* As4 = (float4*)Asm;
#pragma unroll
    for (int it = 0; it < 4; ++it) {
      int i = tid + it * 256;
      int row = i >> 4, kc = i & 15;
      float4 v = make_float4(0.f, 0.f, 0.f, 0.f);
      if (n0 + row < n) v = ((const float4*)(A + (size_t)(n0 + row) * 128))[kc];
      As4[row * 16 + (kc ^ (row & 7))] = v;
    }
    const float4* Wg = (const float4*)WT;
    float4* Ws4 = (float4*)Wsm;
#pragma unroll
    for (int it = 0; it < 8; ++it) {
      int i = tid + it * 256;
      int row = i >> 4, kc = i & 15;
      Ws4[row * 16 + (kc ^ (row & 7))] = Wg[i];
    }
  }
  __syncthreads();
  int lane = tid & 63, wave = tid >> 6;
  int l15 = lane & 15, g = lane >> 4;
  f32x4 acc[8];
#pragma unroll
  for (int f = 0; f < 8; ++f) acc[f] = (f32x4){0.f, 0.f, 0.f, 0.f};
  int arow = wave * 16 + l15;
  const float4* As4 = (const float4*)Asm;
  const float4* Ws4 = (const float4*)Wsm;
#pragma unroll
  for (int kk = 0; kk < 4; ++kk) {
    int kc = kk * 4 + g;
    v8bf a = *(const v8bf*)&As4[arow * 16 + (kc ^ (arow & 7))];
#pragma unroll
    for (int f = 0; f < 8; ++f) {
      int nrow = f * 16 + l15;
      v8bf bf = *(const v8bf*)&Ws4[nrow * 16 + (kc ^ (nrow & 7))];
      acc[f] = __builtin_amdgcn_mfma_f32_16x16x32_bf16(a, bf, acc[f], 0, 0, 0);
    }
  }
  int nodebase = n0 + wave * 16 + g * 4;
#pragma unroll
  for (int f = 0; f < 8; ++f) {
    float bias = b[f * 16 + l15];
    float sf = 0.f;
#pragma unroll
    for (int j = 0; j < 4; ++j) {
      int node = nodebase + j;
      if (node < n) sf += fmaxf(acc[f][j] + bias, 0.f);
    }
    atomicAdd(&colacc[f * 16 + l15], sf);
  }
  __syncthreads();
  if (tid < 128) atomicAdd(&gsum[tid], colacc[tid]);
}

// ---------------- head ----------------

__global__ __launch_bounds__(128) void k_head(const float* __restrict__ gsum,
    const float* __restrict__ Wv1, const float* __restrict__ bv1,
    const float* __restrict__ Wv2, const float* __restrict__ bv2,
    const float* __restrict__ Wa1, const float* __restrict__ ba1,
    const float* __restrict__ Wa2, const float* __restrict__ ba2,
    float* __restrict__ out, int n) {
  __shared__ float gs[HID], ha[HID], red[2], advs[N_ACT], vsh;
  int t = threadIdx.x;
  gs[t] = gsum[t] * (1.0f / (float)n);
  __syncthreads();
  float av = bv1[t], aa = ba1[t];
  for (int k = 0; k < HID; ++k) {
    float gk = gs[k];
    av = fmaf(gk, Wv1[k * HID + t], av);
    aa = fmaf(gk, Wa1[k * HID + t], aa);
  }
  float hv = fmaxf(av, 0.f);
  ha[t] = fmaxf(aa, 0.f);
  float pv = hv * Wv2[t];
#pragma unroll
  for (int o = 32; o > 0; o >>= 1) pv += __shfl_down(pv, o);
  if ((t & 63) == 0) red[t >> 6] = pv;
  __syncthreads();
  if (t == 0) vsh = red[0] + red[1] + bv2[0];
  if (t < N_ACT) {
    float adv = ba2[t];
    for (int j = 0; j < HID; ++j) adv = fmaf(ha[j], Wa2[j * N_ACT + t], adv);
    advs[t] = adv;
  }
  __syncthreads();
  if (t < N_ACT) {
    float m = 0.f;
#pragma unroll
    for (int a = 0; a < N_ACT; ++a) m += advs[a];
    m *= (1.0f / N_ACT);
    out[t] = vsh + advs[t] - m;
  }
}

// ---------------- launch ----------------

extern "C" void kernel_launch(void* const* d_in, const int* in_sizes, int n_in,
                              void* d_out, int out_size, void* d_ws, size_t ws_size,
                              hipStream_t stream) {
  const float* x   = (const float*)d_in[0];
  const int*   ei  = (const int*)d_in[1];
  const float* W1  = (const float*)d_in[2];
  const float* b1  = (const float*)d_in[3];
  const float* W2  = (const float*)d_in[4];
  const float* b2  = (const float*)d_in[5];
  const float* W3  = (const float*)d_in[6];
  const float* b3  = (const float*)d_in[7];
  const float* Wv1 = (const float*)d_in[8];
  const float* bv1 = (const float*)d_in[9];
  const float* Wv2 = (const float*)d_in[10];
  const float* bv2 = (const float*)d_in[11];
  const float* Wa1 = (const float*)d_in[12];
  const float* ba1 = (const float*)d_in[13];
  const float* Wa2 = (const float*)d_in[14];
  const float* ba2 = (const float*)d_in[15];
  float* out = (float*)d_out;

  const int N = in_sizes[0] / F_IN;   // 50000 (< 65536 required for u16 packing)
  const int E = in_sizes[1] / 2;      // 800000
  const int* esrc = ei;
  const int* edst = ei + E;
  const int nbkt = (N + 255) >> 8;    // 196
  const int gE = (E + EPB - 1) / EPB;

  char* p = (char*)d_ws;
  auto alloc = [&](size_t bytes) {
    void* r = (void*)p;
    p += (bytes + 1023) & ~(size_t)1023;
    return r;
  };
  unsigned* ebuf   = (unsigned*)alloc((size_t)nbkt * CAP * 4);     // padded buckets
  int*   gcur      = (int*)alloc((size_t)nbkt * 4);
  int2*  rbe       = (int2*)alloc((size_t)N * 8);
  float* dinv      = (float*)alloc((size_t)N * 4);
  unsigned short* cs = (unsigned short*)alloc((size_t)nbkt * CAP * 2);
  bf16*  xs        = (bf16*)alloc((size_t)N * FP * 2);
  bf16*  WT2       = (bf16*)alloc(128 * 128 * 2);
  bf16*  WT3       = (bf16*)alloc(128 * 128 * 2);
  unsigned* H8a    = (unsigned*)alloc((size_t)N * 128);            // h1 fp8
  unsigned* H8b    = (unsigned*)alloc((size_t)N * 128);            // h2 fp8
  bf16*  A         = (bf16*)alloc((size_t)N * HID * 2);
  float* gsum      = (float*)alloc(HID * 4);

  // CSR build (padded buckets: no histogram prepass, no memset)
  k_init<<<1, 256, 0, stream>>>(gcur, gsum, nbkt);
  k_part<<<gE, 256, 0, stream>>>(esrc, edst, gcur, ebuf, W2, W3, WT2, WT3, E, nbkt);
  k_local<<<nbkt, 256, 0, stream>>>(ebuf, gcur, rbe, dinv, cs, x, xs, N);

  // layer 1 (fused gather16 + GEMM -> fp8 h1)
  k_layer1<<<(N + 63) / 64, 256, 0, stream>>>(xs, dinv, rbe, cs, W1, b1, H8a, N);

  // layers 2/3: fp8 sliced gather (2 x 64B slices), MFMA GEMM
  const int nbx = (N + 15) / 16;
  k_gather<<<nbx * 2, 256, 0, stream>>>(H8a, dinv, rbe, cs, A, N, nbx);
  k_gemm_mfma<<<(N + 63) / 64, 256, 0, stream>>>(A, WT2, b2, dinv, (unsigned char*)H8b, N);
  k_gather<<<nbx * 2, 256, 0, stream>>>(H8b, dinv, rbe, cs, A, N, nbx);
  k_gemm_mfma3<<<(N + 63) / 64, 256, 0, stream>>>(A, WT3, b3, gsum, N);

  // head
  k_head<<<1, 128, 0, stream>>>(gsum, Wv1, bv1, Wv2, bv2, Wa1, ba1, Wa2, ba2, out, N);
}

// Round 11
// 146.891 us; speedup vs baseline: 1.7248x; 1.0713x over previous
//
#include <hip/hip_runtime.h>

#define HID 128
#define F_IN 11
#define FP 16
#define N_ACT 6
#define EPB 2048   // edges per block for k_part (= 8 * 256)
#define LMAX 6144  // k_local LDS staging capacity (edges)
#define CAP 8192   // padded bucket capacity (mean 4096, sigma 64 for uniform dst)

typedef __bf16 bf16;
typedef __bf16 v8bf __attribute__((ext_vector_type(8)));
typedef float f32x4 __attribute__((ext_vector_type(4)));
typedef float v2f __attribute__((ext_vector_type(2)));

__device__ inline float lo16(unsigned u) { return __uint_as_float(u << 16); }
__device__ inline float hi16(unsigned u) { return __uint_as_float(u & 0xffff0000u); }
__device__ inline unsigned pk2(float a, float b) {
  union { bf16 h; unsigned short u; } x, y;
  x.h = (bf16)a; y.h = (bf16)b;
  return ((unsigned)y.u << 16) | x.u;
}
// fp8 e4m3 (OCP) hardware converts — selector args must be literal constants
__device__ inline v2f fp8_dec_lo(unsigned v) {
  return __builtin_amdgcn_cvt_pk_f32_fp8(v, false);
}
__device__ inline v2f fp8_dec_hi(unsigned v) {
  return __builtin_amdgcn_cvt_pk_f32_fp8(v, true);
}
__device__ inline unsigned fp8_enc2_lo(float a, float b, unsigned old) {
  return __builtin_amdgcn_cvt_pk_fp8_f32(a, b, old, false);
}
__device__ inline unsigned fp8_enc2_hi(float a, float b, unsigned old) {
  return __builtin_amdgcn_cvt_pk_fp8_f32(a, b, old, true);
}
__device__ inline unsigned char fp8_enc1(float v) {
  return (unsigned char)(__builtin_amdgcn_cvt_pk_fp8_f32(v, v, 0u, false) & 0xffu);
}

// ---------------- CSR build (padded-bucket counting sort; requires N < 65536) ----------------

__global__ __launch_bounds__(256) void k_init(int* __restrict__ gcur,
                                              float* __restrict__ gsum, int nbkt) {
  int t = threadIdx.x;
  if (t < nbkt) gcur[t] = t * CAP;
  if (t < HID) gsum[t] = 0.f;
}

// block-local sort by bucket + bulk reservation into padded regions + contiguous run writes.
// blocks 0..63 also produce the bf16 weight transposes.
__global__ __launch_bounds__(256) void k_part(const int* __restrict__ esrc,
                                              const int* __restrict__ edst,
                                              int* __restrict__ gcur,
                                              unsigned* __restrict__ ebuf,
                                              const float* __restrict__ W2,
                                              const float* __restrict__ W3,
                                              bf16* __restrict__ WT2,
                                              bf16* __restrict__ WT3,
                                              int E, int nbkt) {
  __shared__ int hist[256], lofs[256], lcur[256], gbase[256];
  __shared__ unsigned sbuf[EPB];
  int t = threadIdx.x;
  hist[t] = 0;
  if (blockIdx.x < 64) {   // WT[n][k] = bf16(W[k][n])
    int i = blockIdx.x * 256 + t;
    int nn = i >> 7, k = i & 127;
    WT2[i] = (bf16)W2[k * 128 + nn];
    WT3[i] = (bf16)W3[k * 128 + nn];
  }
  __syncthreads();
  int start = blockIdx.x * EPB, end = min(E, start + EPB);
  unsigned u[8];
#pragma unroll
  for (int i = 0; i < 8; ++i) {
    int e = start + t + i * 256;
    if (e < end) {
      int s = esrc[e], d = edst[e];
      u[i] = ((unsigned)d << 16) | (unsigned)s;
      atomicAdd(&hist[d >> 8], 1);
    }
  }
  __syncthreads();
  int h = hist[t];
  lofs[t] = h;
  __syncthreads();
  for (int off = 1; off < 256; off <<= 1) {
    int x = (t >= off) ? lofs[t - off] : 0;
    __syncthreads();
    lofs[t] += x;
    __syncthreads();
  }
  lcur[t] = lofs[t] - h;
  if (t < nbkt && h) gbase[t] = atomicAdd(&gcur[t], h);   // bulk reservation
  __syncthreads();
#pragma unroll
  for (int i = 0; i < 8; ++i) {
    int e = start + t + i * 256;
    if (e < end) {
      int b = (int)(u[i] >> 24);
      int p = atomicAdd(&lcur[b], 1);
      sbuf[p] = u[i];
    }
  }
  __syncthreads();
  int m = end - start;
  for (int i = t; i < m; i += 256) {
    unsigned v = sbuf[i];
    int b = (int)(v >> 24);
    int excl = lofs[b] - hist[b];
    ebuf[gbase[b] + (i - excl)] = v;
  }
}

// one workgroup per bucket (1024 threads for latency hiding): LDS-staged hist + scan + fill.
// Writes rbe(int2: edge run begin/end), dinv, cs(ushort), and xs (= x*dinv bf16 padded).
__global__ __launch_bounds__(1024) void k_local(const unsigned* __restrict__ ebuf,
                                                const int* __restrict__ gcur,
                                                int2* __restrict__ rbe,
                                                float* __restrict__ dinv,
                                                unsigned short* __restrict__ cs,
                                                const float* __restrict__ x,
                                                bf16* __restrict__ xs, int n) {
  __shared__ int hist[256], lofs[256], cur[256];
  __shared__ float dsh[256];
  __shared__ unsigned sb[LMAX];
  int b = blockIdx.x, t = threadIdx.x;
  int rb = b * CAP, re = gcur[b];
  int m = re - rb;
  int nbase = b << 8;
  bool fit = (m <= LMAX);
  if (t < 256) hist[t] = 0;
  __syncthreads();
  if (fit) {
    for (int i = t; i < m; i += 1024) {
      unsigned u = ebuf[rb + i];
      sb[i] = u;
      atomicAdd(&hist[(int)(u >> 16) - nbase], 1);
    }
  } else {
    for (int i = t; i < m; i += 1024)
      atomicAdd(&hist[(int)(ebuf[rb + i] >> 16) - nbase], 1);
  }
  __syncthreads();
  int h = 0;
  if (t < 256) { h = hist[t]; lofs[t] = h; }
  __syncthreads();
  for (int off = 1; off < 256; off <<= 1) {
    int v = (t < 256 && t >= off) ? lofs[t - off] : 0;
    __syncthreads();
    if (t < 256) lofs[t] += v;
    __syncthreads();
  }
  if (t < 256) {
    int excl = lofs[t] - h;
    cur[t] = rb + excl;
    float dv = rsqrtf((float)h + 1.0f);
    dsh[t] = dv;
    int g = nbase + t;
    if (g < n) {
      rbe[g] = make_int2(rb + excl, rb + lofs[t]);
      dinv[g] = dv;
    }
  }
  __syncthreads();
  if (fit) {
    for (int i = t; i < m; i += 1024) {
      unsigned u = sb[i];
      int p = atomicAdd(&cur[(int)(u >> 16) - nbase], 1);
      cs[p] = (unsigned short)(u & 0xffffu);
    }
  } else {
    for (int i = t; i < m; i += 1024) {
      unsigned u = ebuf[rb + i];
      int p = atomicAdd(&cur[(int)(u >> 16) - nbase], 1);
      cs[p] = (unsigned short)(u & 0xffffu);
    }
  }
  // xs = x * dinv (bf16, padded to 16 cols) for this bucket's nodes
  for (int i = t; i < 256 * FP; i += 1024) {
    int node = nbase + (i >> 4), c = i & 15;
    if (node < n)
      xs[(size_t)node * FP + c] =
          (bf16)((c < F_IN) ? x[(size_t)node * F_IN + c] * dsh[i >> 4] : 0.f);
  }
}

// ---------------- layer 1: fused gather16 + 11->128 GEMM -> h1 (fp8) ----------------

__global__ __launch_bounds__(256) void k_layer1(const bf16* __restrict__ xs,
                                                const float* __restrict__ dinv,
                                                const int2* __restrict__ rbe,
                                                const unsigned short* __restrict__ cs,
                                                const float* __restrict__ W1,
                                                const float* __restrict__ b1,
                                                unsigned* __restrict__ H8, int n) {
  __shared__ float Ws[F_IN * HID];
  __shared__ float A1s[64][17];
  int tid = threadIdx.x;
  int n0 = blockIdx.x * 64;
  for (int i = tid; i < F_IN * HID; i += 256) Ws[i] = W1[i];
  int wave = tid >> 6, lane = tid & 63;
  int g8 = lane >> 3, c = lane & 7;
  const unsigned* xs2 = (const unsigned*)xs;
#pragma unroll
  for (int r = 0; r < 2; ++r) {
    int row = wave * 16 + r * 8 + g8;
    int node = n0 + row;
    unsigned sv = 0;
    int j = 0, jend = 0;
    float dd = 0.f;
    if (node < n) {
      sv = xs2[(size_t)node * 8 + c];
      int2 be = rbe[node];
      j = be.x; jend = be.y;
      dd = dinv[node];
    }
    float ax = lo16(sv), ay = hi16(sv);
    for (; j < jend; j += 4) {
#pragma unroll
      for (int k = 0; k < 4; ++k) {
        int jj = j + k;
        bool ok = jj < jend;
        int sidx = cs[ok ? jj : jend - 1];
        unsigned v = xs2[(size_t)sidx * 8 + c];
        float mm = ok ? 1.f : 0.f;
        ax = fmaf(lo16(v), mm, ax);
        ay = fmaf(hi16(v), mm, ay);
      }
    }
    A1s[row][c * 2] = ax * dd;
    A1s[row][c * 2 + 1] = ay * dd;
  }
  __syncthreads();
  int tc = tid & 15, tr = tid >> 4;
  float bb[8];
#pragma unroll
  for (int j = 0; j < 8; ++j) bb[j] = b1[tc * 8 + j];
#pragma unroll
  for (int i = 0; i < 4; ++i) {
    int row = tr * 4 + i;
    int node = n0 + row;
    if (node >= n) continue;
    float acc[8];
#pragma unroll
    for (int j = 0; j < 8; ++j) acc[j] = 0.f;
#pragma unroll
    for (int k = 0; k < F_IN; ++k) {
      float xk = A1s[row][k];
      const float* wr = &Ws[k * HID + tc * 8];
#pragma unroll
      for (int j = 0; j < 8; ++j) acc[j] = fmaf(xk, wr[j], acc[j]);
    }
    float dd = dinv[node];
    float o[8];
#pragma unroll
    for (int j = 0; j < 8; ++j) o[j] = fmaxf(acc[j] + bb[j], 0.f) * dd;
    unsigned w0 = 0, w1 = 0;
    w0 = fp8_enc2_lo(o[0], o[1], w0);
    w0 = fp8_enc2_hi(o[2], o[3], w0);
    w1 = fp8_enc2_lo(o[4], o[5], w1);
    w1 = fp8_enc2_hi(o[6], o[7], w1);
    ((uint2*)H8)[(size_t)node * 16 + tc] = make_uint2(w0, w1);
  }
}

// ---------------- layers 2/3: fused fp8-gather + MFMA GEMM (512 thr, 16KB LDS) ----------------

// Gather phase: 8 waves x 8 nodes; each wave handles 2 nodes at a time (32 lanes/node,
// full 128B fp8 row in one pass), accumulates f32, writes bf16 swizzled A-tile to LDS.
// MFMA phase: wave -> rows (wave&3)*16, cols (wave>>2)*64; B-fragments read directly from
// global WT (32KB, L1/L2-resident). FINAL=false: H8 = fp8(relu(acc+b)*dinv).
// FINAL=true: column-sum relu(acc+b) into gsum.
template <bool FINAL>
__global__ __launch_bounds__(512) void k_layer(const unsigned* __restrict__ tab,
                                               const float* __restrict__ dinv,
                                               const int2* __restrict__ rbe,
                                               const unsigned short* __restrict__ cs,
                                               const bf16* __restrict__ WT,
                                               const float* __restrict__ b,
                                               unsigned char* __restrict__ H8,
                                               float* __restrict__ gsum, int n) {
  __shared__ bf16 Asm[64 * 128];   // 16 KB, XOR-swizzled 16B chunks
  __shared__ float colacc[128];
  int tid = threadIdx.x;
  int n0 = blockIdx.x * 64;
  if (FINAL && tid < 128) colacc[tid] = 0.f;
  int wave = tid >> 6, lane = tid & 63;
  int sub = lane >> 5;        // node within pair
  int c = lane & 31;          // u32 col (4 fp8) within 128B row
#pragma unroll
  for (int r = 0; r < 4; ++r) {
    int row = wave * 8 + r * 2 + sub;
    int node = n0 + row;
    float a0 = 0.f, a1 = 0.f, a2 = 0.f, a3 = 0.f, dd = 0.f;
    int j = 0, jend = 0;
    if (node < n) {
      unsigned sv = tab[(size_t)node * 32 + c];
      v2f lo = fp8_dec_lo(sv), hi = fp8_dec_hi(sv);
      a0 = lo.x; a1 = lo.y; a2 = hi.x; a3 = hi.y;
      int2 be = rbe[node];
      j = be.x; jend = be.y;
      dd = dinv[node];
    }
    for (; j < jend; j += 8) {
#pragma unroll
      for (int k = 0; k < 8; ++k) {
        int jj = j + k;
        bool ok = jj < jend;
        int sidx = cs[ok ? jj : jend - 1];
        unsigned v = tab[(size_t)sidx * 32 + c];
        float mm = ok ? 1.f : 0.f;
        v2f lo = fp8_dec_lo(v), hi = fp8_dec_hi(v);
        a0 = fmaf(lo.x, mm, a0);
        a1 = fmaf(lo.y, mm, a1);
        a2 = fmaf(hi.x, mm, a2);
        a3 = fmaf(hi.y, mm, a3);
      }
    }
    int kc = c >> 1, half = c & 1;
    uint2 w = make_uint2(pk2(a0 * dd, a1 * dd), pk2(a2 * dd, a3 * dd));
    *(uint2*)((char*)Asm + row * 256 + ((kc ^ (row & 7)) << 4) + (half << 3)) = w;
  }
  __syncthreads();
  // MFMA: 16x16x32 bf16; A from swizzled LDS, B (16B frags) from global WT
  int l15 = lane & 15, g = lane >> 4;
  int rg = (wave & 3) * 16;
  int cg = (wave >> 2) * 64;
  f32x4 acc[4];
#pragma unroll
  for (int f = 0; f < 4; ++f) acc[f] = (f32x4){0.f, 0.f, 0.f, 0.f};
  int arow = rg + l15;
#pragma unroll
  for (int kk = 0; kk < 4; ++kk) {
    int kc = kk * 4 + g;
    v8bf a = *(const v8bf*)((const char*)Asm + arow * 256 + ((kc ^ (arow & 7)) << 4));
#pragma unroll
    for (int f = 0; f < 4; ++f) {
      int nrow = cg + f * 16 + l15;
      v8bf bfr = *(const v8bf*)(WT + (size_t)nrow * 128 + kc * 8);
      acc[f] = __builtin_amdgcn_mfma_f32_16x16x32_bf16(a, bfr, acc[f], 0, 0, 0);
    }
  }
  int nodebase = n0 + rg + g * 4;
  if (FINAL) {
#pragma unroll
    for (int f = 0; f < 4; ++f) {
      int col = cg + f * 16 + l15;
      float bias = b[col];
      float sf = 0.f;
#pragma unroll
      for (int j = 0; j < 4; ++j) {
        int node = nodebase + j;
        if (node < n) sf += fmaxf(acc[f][j] + bias, 0.f);
      }
      atomicAdd(&colacc[col], sf);
    }
    __syncthreads();
    if (tid < 128) atomicAdd(&gsum[tid], colacc[tid]);
  } else {
    float dv[4];
#pragma unroll
    for (int j = 0; j < 4; ++j)
      dv[j] = (nodebase + j < n) ? dinv[nodebase + j] : 1.f;
#pragma unroll
    for (int f = 0; f < 4; ++f) {
      int col = cg + f * 16 + l15;
      float bias = b[col];
#pragma unroll
      for (int j = 0; j < 4; ++j) {
        int node = nodebase + j;
        if (node < n) {
          float v = fmaxf(acc[f][j] + bias, 0.f) * dv[j];
          H8[(size_t)node * 128 + col] = fp8_enc1(v);
        }
      }
    }
  }
}

// ---------------- head ----------------

__global__ __launch_bounds__(128) void k_head(const float* __restrict__ gsum,
    const float* __restrict__ Wv1, const float* __restrict__ bv1,
    const float* __restrict__ Wv2, const float* __restrict__ bv2,
    const float* __restrict__ Wa1, const float* __restrict__ ba1,
    const float* __restrict__ Wa2, const float* __restrict__ ba2,
    float* __restrict__ out, int n) {
  __shared__ float gs[HID], ha[HID], red[2], advs[N_ACT], vsh;
  int t = threadIdx.x;
  gs[t] = gsum[t] * (1.0f / (float)n);
  __syncthreads();
  float av = bv1[t], aa = ba1[t];
  for (int k = 0; k < HID; ++k) {
    float gk = gs[k];
    av = fmaf(gk, Wv1[k * HID + t], av);
    aa = fmaf(gk, Wa1[k * HID + t], aa);
  }
  float hv = fmaxf(av, 0.f);
  ha[t] = fmaxf(aa, 0.f);
  float pv = hv * Wv2[t];
#pragma unroll
  for (int o = 32; o > 0; o >>= 1) pv += __shfl_down(pv, o);
  if ((t & 63) == 0) red[t >> 6] = pv;
  __syncthreads();
  if (t == 0) vsh = red[0] + red[1] + bv2[0];
  if (t < N_ACT) {
    float adv = ba2[t];
    for (int j = 0; j < HID; ++j) adv = fmaf(ha[j], Wa2[j * N_ACT + t], adv);
    advs[t] = adv;
  }
  __syncthreads();
  if (t < N_ACT) {
    float m = 0.f;
#pragma unroll
    for (int a = 0; a < N_ACT; ++a) m += advs[a];
    m *= (1.0f / N_ACT);
    out[t] = vsh + advs[t] - m;
  }
}

// ---------------- launch ----------------

extern "C" void kernel_launch(void* const* d_in, const int* in_sizes, int n_in,
                              void* d_out, int out_size, void* d_ws, size_t ws_size,
                              hipStream_t stream) {
  const float* x   = (const float*)d_in[0];
  const int*   ei  = (const int*)d_in[1];
  const float* W1  = (const float*)d_in[2];
  const float* b1  = (const float*)d_in[3];
  const float* W2  = (const float*)d_in[4];
  const float* b2  = (const float*)d_in[5];
  const float* W3  = (const float*)d_in[6];
  const float* b3  = (const float*)d_in[7];
  const float* Wv1 = (const float*)d_in[8];
  const float* bv1 = (const float*)d_in[9];
  const float* Wv2 = (const float*)d_in[10];
  const float* bv2 = (const float*)d_in[11];
  const float* Wa1 = (const float*)d_in[12];
  const float* ba1 = (const float*)d_in[13];
  const float* Wa2 = (const float*)d_in[14];
  const float* ba2 = (const float*)d_in[15];
  float* out = (float*)d_out;

  const int N = in_sizes[0] / F_IN;   // 50000 (< 65536 required for u16 packing)
  const int E = in_sizes[1] / 2;      // 800000
  const int* esrc = ei;
  const int* edst = ei + E;
  const int nbkt = (N + 255) >> 8;    // 196
  const int gE = (E + EPB - 1) / EPB;

  char* p = (char*)d_ws;
  auto alloc = [&](size_t bytes) {
    void* r = (void*)p;
    p += (bytes + 1023) & ~(size_t)1023;
    return r;
  };
  unsigned* ebuf   = (unsigned*)alloc((size_t)nbkt * CAP * 4);     // padded buckets
  int*   gcur      = (int*)alloc((size_t)nbkt * 4);
  int2*  rbe       = (int2*)alloc((size_t)N * 8);
  float* dinv      = (float*)alloc((size_t)N * 4);
  unsigned short* cs = (unsigned short*)alloc((size_t)nbkt * CAP * 2);
  bf16*  xs        = (bf16*)alloc((size_t)N * FP * 2);
  bf16*  WT2       = (bf16*)alloc(128 * 128 * 2);
  bf16*  WT3       = (bf16*)alloc(128 * 128 * 2);
  unsigned* H8a    = (unsigned*)alloc((size_t)N * 128);            // h1 fp8
  unsigned* H8b    = (unsigned*)alloc((size_t)N * 128);            // h2 fp8
  float* gsum      = (float*)alloc(HID * 4);

  // CSR build (padded buckets)
  k_init<<<1, 256, 0, stream>>>(gcur, gsum, nbkt);
  k_part<<<gE, 256, 0, stream>>>(esrc, edst, gcur, ebuf, W2, W3, WT2, WT3, E, nbkt);
  k_local<<<nbkt, 1024, 0, stream>>>(ebuf, gcur, rbe, dinv, cs, x, xs, N);

  // layer 1 (fused gather16 + GEMM -> fp8 h1)
  k_layer1<<<(N + 63) / 64, 256, 0, stream>>>(xs, dinv, rbe, cs, W1, b1, H8a, N);

  // layers 2/3: fused fp8 gather + MFMA GEMM
  int gL = (N + 63) / 64;
  k_layer<false><<<gL, 512, 0, stream>>>(H8a, dinv, rbe, cs, WT2, b2,
                                         (unsigned char*)H8b, gsum, N);
  k_layer<true><<<gL, 512, 0, stream>>>(H8b, dinv, rbe, cs, WT3, b3,
                                        (unsigned char*)nullptr, gsum, N);

  // head
  k_head<<<1, 128, 0, stream>>>(gsum, Wv1, bv1, Wv2, bv2, Wa1, ba1, Wa2, ba2, out, N);
}

// Round 12
// 145.347 us; speedup vs baseline: 1.7431x; 1.0106x over previous
//
#include <hip/hip_runtime.h>

#define HID 128
#define F_IN 11
#define FP 16
#define N_ACT 6
#define EPB 2048   // edges per block for k_part (= 8 * 256)
#define LMAX 6144  // k_local LDS staging capacity (edges)
#define CAP 8192   // padded bucket capacity (mean 4096 real, ~5900 padded)

typedef __bf16 bf16;
typedef __bf16 v8bf __attribute__((ext_vector_type(8)));
typedef float f32x4 __attribute__((ext_vector_type(4)));
typedef float v2f __attribute__((ext_vector_type(2)));

__device__ inline float lo16(unsigned u) { return __uint_as_float(u << 16); }
__device__ inline float hi16(unsigned u) { return __uint_as_float(u & 0xffff0000u); }
__device__ inline unsigned pk2(float a, float b) {
  union { bf16 h; unsigned short u; } x, y;
  x.h = (bf16)a; y.h = (bf16)b;
  return ((unsigned)y.u << 16) | x.u;
}
// fp8 e4m3 (OCP) hardware converts — selector args must be literal constants
__device__ inline v2f fp8_dec_lo(unsigned v) {
  return __builtin_amdgcn_cvt_pk_f32_fp8(v, false);
}
__device__ inline v2f fp8_dec_hi(unsigned v) {
  return __builtin_amdgcn_cvt_pk_f32_fp8(v, true);
}
__device__ inline unsigned fp8_enc2_lo(float a, float b, unsigned old) {
  return __builtin_amdgcn_cvt_pk_fp8_f32(a, b, old, false);
}
__device__ inline unsigned fp8_enc2_hi(float a, float b, unsigned old) {
  return __builtin_amdgcn_cvt_pk_fp8_f32(a, b, old, true);
}
__device__ inline unsigned char fp8_enc1(float v) {
  return (unsigned char)(__builtin_amdgcn_cvt_pk_fp8_f32(v, v, 0u, false) & 0xffu);
}

// ---------------- init: cursors, gsum, dummy rows (index N) ----------------

__global__ __launch_bounds__(256) void k_init(int* __restrict__ gcur,
                                              float* __restrict__ gsum,
                                              unsigned* __restrict__ xsN,
                                              unsigned* __restrict__ H8aN,
                                              unsigned* __restrict__ H8bN, int nbkt) {
  int t = threadIdx.x;
  if (t < nbkt) gcur[t] = t * CAP;
  if (t < HID) gsum[t] = 0.f;
  if (t < 8) xsN[t] = 0u;                       // xs row N (16 bf16)
  if (t < 32) { H8aN[t] = 0u; H8bN[t] = 0u; }   // fp8 rows N (128 fp8)
}

// ---------------- CSR build (padded-bucket counting sort; requires N < 65535) ----------------

// block-local sort by bucket + bulk reservation into padded regions + contiguous run writes.
// blocks 0..63 also produce the bf16 weight transposes.
__global__ __launch_bounds__(256) void k_part(const int* __restrict__ esrc,
                                              const int* __restrict__ edst,
                                              int* __restrict__ gcur,
                                              unsigned* __restrict__ ebuf,
                                              const float* __restrict__ W2,
                                              const float* __restrict__ W3,
                                              bf16* __restrict__ WT2,
                                              bf16* __restrict__ WT3,
                                              int E, int nbkt) {
  __shared__ int hist[256], lofs[256], lcur[256], gbase[256];
  __shared__ unsigned sbuf[EPB];
  int t = threadIdx.x;
  hist[t] = 0;
  if (blockIdx.x < 64) {   // WT[n][k] = bf16(W[k][n])
    int i = blockIdx.x * 256 + t;
    int nn = i >> 7, k = i & 127;
    WT2[i] = (bf16)W2[k * 128 + nn];
    WT3[i] = (bf16)W3[k * 128 + nn];
  }
  __syncthreads();
  int start = blockIdx.x * EPB, end = min(E, start + EPB);
  unsigned u[8];
#pragma unroll
  for (int i = 0; i < 8; ++i) {
    int e = start + t + i * 256;
    if (e < end) {
      int s = esrc[e], d = edst[e];
      u[i] = ((unsigned)d << 16) | (unsigned)s;
      atomicAdd(&hist[d >> 8], 1);
    }
  }
  __syncthreads();
  int h = hist[t];
  lofs[t] = h;
  __syncthreads();
  for (int off = 1; off < 256; off <<= 1) {
    int x = (t >= off) ? lofs[t - off] : 0;
    __syncthreads();
    lofs[t] += x;
    __syncthreads();
  }
  lcur[t] = lofs[t] - h;
  if (t < nbkt && h) gbase[t] = atomicAdd(&gcur[t], h);   // bulk reservation
  __syncthreads();
#pragma unroll
  for (int i = 0; i < 8; ++i) {
    int e = start + t + i * 256;
    if (e < end) {
      int b = (int)(u[i] >> 24);
      int p = atomicAdd(&lcur[b], 1);
      sbuf[p] = u[i];
    }
  }
  __syncthreads();
  int m = end - start;
  for (int i = t; i < m; i += 256) {
    unsigned v = sbuf[i];
    int b = (int)(v >> 24);
    int excl = lofs[b] - hist[b];
    ebuf[gbase[b] + (i - excl)] = v;
  }
}

// one workgroup per bucket (1024 threads): LDS-staged hist + scan + fill.
// Edge runs PADDED to multiples of 16 with dummy src=N (zero row). Writes rbe (padded
// begin/end), dinv, cs(ushort), and xs (= x*dinv bf16 padded to 16 cols).
__global__ __launch_bounds__(1024) void k_local(const unsigned* __restrict__ ebuf,
                                                const int* __restrict__ gcur,
                                                int2* __restrict__ rbe,
                                                float* __restrict__ dinv,
                                                unsigned short* __restrict__ cs,
                                                const float* __restrict__ x,
                                                bf16* __restrict__ xs, int n) {
  __shared__ int hist[256], lofs[256], cur[256], realh[256];
  __shared__ float dsh[256];
  __shared__ unsigned sb[LMAX];
  int b = blockIdx.x, t = threadIdx.x;
  int rb = b * CAP, re = gcur[b];
  int m = re - rb;
  int nbase = b << 8;
  bool fit = (m <= LMAX);
  if (t < 256) hist[t] = 0;
  __syncthreads();
  if (fit) {
    for (int i = t; i < m; i += 1024) {
      unsigned u = ebuf[rb + i];
      sb[i] = u;
      atomicAdd(&hist[(int)(u >> 16) - nbase], 1);
    }
  } else {
    for (int i = t; i < m; i += 1024)
      atomicAdd(&hist[(int)(ebuf[rb + i] >> 16) - nbase], 1);
  }
  __syncthreads();
  int h = 0, hp = 0;
  if (t < 256) {
    h = hist[t];
    realh[t] = h;
    hp = (h + 15) & ~15;       // pad to multiple of 16
    lofs[t] = hp;
  }
  __syncthreads();
  for (int off = 1; off < 256; off <<= 1) {
    int v = (t < 256 && t >= off) ? lofs[t - off] : 0;
    __syncthreads();
    if (t < 256) lofs[t] += v;
    __syncthreads();
  }
  if (t < 256) {
    int pexcl = lofs[t] - hp;
    cur[t] = rb + pexcl;
    float dv = rsqrtf((float)h + 1.0f);
    dsh[t] = dv;
    int g = nbase + t;
    if (g < n) {
      rbe[g] = make_int2(rb + pexcl, rb + pexcl + hp);
      dinv[g] = dv;
    }
  }
  __syncthreads();
  if (fit) {
    for (int i = t; i < m; i += 1024) {
      unsigned u = sb[i];
      int p = atomicAdd(&cur[(int)(u >> 16) - nbase], 1);
      cs[p] = (unsigned short)(u & 0xffffu);
    }
  } else {
    for (int i = t; i < m; i += 1024) {
      unsigned u = ebuf[rb + i];
      int p = atomicAdd(&cur[(int)(u >> 16) - nbase], 1);
      cs[p] = (unsigned short)(u & 0xffffu);
    }
  }
  __syncthreads();
  // pad each node's run [h, hp) with dummy src = n (zero row)
  if (t < 256) {
    int hh = realh[t];
    int hpp = (hh + 15) & ~15;
    int base = cur[t];  // == run start + hh after fill
    for (int i = hh; i < hpp; ++i) cs[base + (i - hh)] = (unsigned short)n;
  }
  // xs = x * dinv (bf16, padded to 16 cols) for this bucket's nodes
  for (int i = t; i < 256 * FP; i += 1024) {
    int node = nbase + (i >> 4), c = i & 15;
    if (node < n)
      xs[(size_t)node * FP + c] =
          (bf16)((c < F_IN) ? x[(size_t)node * F_IN + c] * dsh[i >> 4] : 0.f);
  }
}

// ---------------- layer 1: fused gather16 + 11->128 GEMM -> h1 (fp8) ----------------

__global__ __launch_bounds__(256) void k_layer1(const bf16* __restrict__ xs,
                                                const float* __restrict__ dinv,
                                                const int2* __restrict__ rbe,
                                                const unsigned short* __restrict__ cs,
                                                const float* __restrict__ W1,
                                                const float* __restrict__ b1,
                                                unsigned* __restrict__ H8, int n) {
  __shared__ float Ws[F_IN * HID];
  __shared__ float A1s[64][17];
  int tid = threadIdx.x;
  int n0 = blockIdx.x * 64;
  for (int i = tid; i < F_IN * HID; i += 256) Ws[i] = W1[i];
  int wave = tid >> 6, lane = tid & 63;
  int g8 = lane >> 3, c = lane & 7;
  const unsigned* xs2 = (const unsigned*)xs;
#pragma unroll
  for (int r = 0; r < 2; ++r) {
    int row = wave * 16 + r * 8 + g8;
    int node = n0 + row;
    unsigned sv = 0;
    int j = 0, jend = 0;
    float dd = 0.f;
    if (node < n) {
      sv = xs2[(size_t)node * 8 + c];
      int2 be = rbe[node];
      j = be.x; jend = be.y;
      dd = dinv[node];
    }
    float ax = lo16(sv), ay = hi16(sv);
    for (; j < jend; j += 4) {    // padded: no masking; dummies read zero row
#pragma unroll
      for (int k = 0; k < 4; ++k) {
        unsigned v = xs2[(size_t)cs[j + k] * 8 + c];
        ax += lo16(v);
        ay += hi16(v);
      }
    }
    A1s[row][c * 2] = ax * dd;
    A1s[row][c * 2 + 1] = ay * dd;
  }
  __syncthreads();
  int tc = tid & 15, tr = tid >> 4;
  float bb[8];
#pragma unroll
  for (int j = 0; j < 8; ++j) bb[j] = b1[tc * 8 + j];
#pragma unroll
  for (int i = 0; i < 4; ++i) {
    int row = tr * 4 + i;
    int node = n0 + row;
    if (node >= n) continue;
    float acc[8];
#pragma unroll
    for (int j = 0; j < 8; ++j) acc[j] = 0.f;
#pragma unroll
    for (int k = 0; k < F_IN; ++k) {
      float xk = A1s[row][k];
      const float* wr = &Ws[k * HID + tc * 8];
#pragma unroll
      for (int j = 0; j < 8; ++j) acc[j] = fmaf(xk, wr[j], acc[j]);
    }
    float dd = dinv[node];
    float o[8];
#pragma unroll
    for (int j = 0; j < 8; ++j) o[j] = fmaxf(acc[j] + bb[j], 0.f) * dd;
    unsigned w0 = 0, w1 = 0;
    w0 = fp8_enc2_lo(o[0], o[1], w0);
    w0 = fp8_enc2_hi(o[2], o[3], w0);
    w1 = fp8_enc2_lo(o[4], o[5], w1);
    w1 = fp8_enc2_hi(o[6], o[7], w1);
    ((uint2*)H8)[(size_t)node * 16 + tc] = make_uint2(w0, w1);
  }
}

// ---------------- layers 2/3: fused fp8-gather + MFMA (32-node tile, 512 thr) ----------------

// Gather: 8 waves x 4 nodes (2 rounds of node-pairs; 32 lanes/node = full 128B row).
// cs prefetched as uint4 (8 indices/load); 16 independent tab loads per batch; packed adds.
// MFMA: 2 frags/wave; B-fragments straight from global WT (L2-resident).
template <bool FINAL>
__global__ __launch_bounds__(512) void k_layer(const unsigned* __restrict__ tab,
                                               const float* __restrict__ dinv,
                                               const int2* __restrict__ rbe,
                                               const unsigned short* __restrict__ cs,
                                               const bf16* __restrict__ WT,
                                               const float* __restrict__ b,
                                               unsigned char* __restrict__ H8,
                                               float* __restrict__ gsum, int n) {
  __shared__ bf16 Asm[32 * 128];   // 8 KB, XOR-swizzled 16B chunks
  __shared__ float colacc[128];
  int tid = threadIdx.x;
  int n0 = blockIdx.x * 32;
  if (FINAL && tid < 128) colacc[tid] = 0.f;
  int wave = tid >> 6, lane = tid & 63;
  int sub = lane >> 5;        // node within pair
  int c = lane & 31;          // u32 col (4 fp8) within 128B row
#pragma unroll
  for (int r = 0; r < 2; ++r) {
    int row = wave * 4 + r * 2 + sub;
    int node = n0 + row;
    v2f acc01 = (v2f){0.f, 0.f}, acc23 = (v2f){0.f, 0.f};
    float dd = 0.f;
    int j = 0, jend = 0;
    if (node < n) {
      unsigned sv = tab[(size_t)node * 32 + c];
      acc01 = fp8_dec_lo(sv);
      acc23 = fp8_dec_hi(sv);
      int2 be = rbe[node];
      j = be.x; jend = be.y;
      dd = dinv[node];
    }
    for (; j < jend; j += 16) {   // padded: full batches, dummies hit hot zero row
      uint4 cv0 = *(const uint4*)(cs + j);
      uint4 cv1 = *(const uint4*)(cs + j + 8);
      unsigned sx[16];
      sx[0] = cv0.x & 0xffffu;  sx[1] = cv0.x >> 16;
      sx[2] = cv0.y & 0xffffu;  sx[3] = cv0.y >> 16;
      sx[4] = cv0.z & 0xffffu;  sx[5] = cv0.z >> 16;
      sx[6] = cv0.w & 0xffffu;  sx[7] = cv0.w >> 16;
      sx[8] = cv1.x & 0xffffu;  sx[9] = cv1.x >> 16;
      sx[10] = cv1.y & 0xffffu; sx[11] = cv1.y >> 16;
      sx[12] = cv1.z & 0xffffu; sx[13] = cv1.z >> 16;
      sx[14] = cv1.w & 0xffffu; sx[15] = cv1.w >> 16;
      unsigned vv[16];
#pragma unroll
      for (int k = 0; k < 16; ++k) vv[k] = tab[(size_t)sx[k] * 32 + c];
#pragma unroll
      for (int k = 0; k < 16; ++k) {
        acc01 += fp8_dec_lo(vv[k]);
        acc23 += fp8_dec_hi(vv[k]);
      }
    }
    int kc = c >> 1, half = c & 1;
    uint2 w = make_uint2(pk2(acc01.x * dd, acc01.y * dd),
                         pk2(acc23.x * dd, acc23.y * dd));
    *(uint2*)((char*)Asm + row * 256 + ((kc ^ (row & 7)) << 4) + (half << 3)) = w;
  }
  __syncthreads();
  // MFMA: 16x16x32 bf16; A from swizzled LDS, B (16B frags) from global WT
  int l15 = lane & 15, g = lane >> 4;
  int rg = (wave & 1) * 16;
  int cbase = (wave >> 1) * 32;
  f32x4 acc[2];
#pragma unroll
  for (int f = 0; f < 2; ++f) acc[f] = (f32x4){0.f, 0.f, 0.f, 0.f};
  int arow = rg + l15;
#pragma unroll
  for (int kk = 0; kk < 4; ++kk) {
    int kc = kk * 4 + g;
    v8bf a = *(const v8bf*)((const char*)Asm + arow * 256 + ((kc ^ (arow & 7)) << 4));
#pragma unroll
    for (int f = 0; f < 2; ++f) {
      int nrow = cbase + f * 16 + l15;
      v8bf bfr = *(const v8bf*)(WT + (size_t)nrow * 128 + kc * 8);
      acc[f] = __builtin_amdgcn_mfma_f32_16x16x32_bf16(a, bfr, acc[f], 0, 0, 0);
    }
  }
  int nodebase = n0 + rg + g * 4;
  if (FINAL) {
#pragma unroll
    for (int f = 0; f < 2; ++f) {
      int col = cbase + f * 16 + l15;
      float bias = b[col];
      float sf = 0.f;
#pragma unroll
      for (int j = 0; j < 4; ++j) {
        int node = nodebase + j;
        if (node < n) sf += fmaxf(acc[f][j] + bias, 0.f);
      }
      atomicAdd(&colacc[col], sf);
    }
    __syncthreads();
    if (tid < 128) atomicAdd(&gsum[tid], colacc[tid]);
  } else {
    float dv[4];
#pragma unroll
    for (int j = 0; j < 4; ++j)
      dv[j] = (nodebase + j < n) ? dinv[nodebase + j] : 1.f;
#pragma unroll
    for (int f = 0; f < 2; ++f) {
      int col = cbase + f * 16 + l15;
      float bias = b[col];
#pragma unroll
      for (int j = 0; j < 4; ++j) {
        int node = nodebase + j;
        if (node < n) {
          float v = fmaxf(acc[f][j] + bias, 0.f) * dv[j];
          H8[(size_t)node * 128 + col] = fp8_enc1(v);
        }
      }
    }
  }
}

// ---------------- head ----------------

__global__ __launch_bounds__(128) void k_head(const float* __restrict__ gsum,
    const float* __restrict__ Wv1, const float* __restrict__ bv1,
    const float* __restrict__ Wv2, const float* __restrict__ bv2,
    const float* __restrict__ Wa1, const float* __restrict__ ba1,
    const float* __restrict__ Wa2, const float* __restrict__ ba2,
    float* __restrict__ out, int n) {
  __shared__ float gs[HID], ha[HID], red[2], advs[N_ACT], vsh;
  int t = threadIdx.x;
  gs[t] = gsum[t] * (1.0f / (float)n);
  __syncthreads();
  float av = bv1[t], aa = ba1[t];
  for (int k = 0; k < HID; ++k) {
    float gk = gs[k];
    av = fmaf(gk, Wv1[k * HID + t], av);
    aa = fmaf(gk, Wa1[k * HID + t], aa);
  }
  float hv = fmaxf(av, 0.f);
  ha[t] = fmaxf(aa, 0.f);
  float pv = hv * Wv2[t];
#pragma unroll
  for (int o = 32; o > 0; o >>= 1) pv += __shfl_down(pv, o);
  if ((t & 63) == 0) red[t >> 6] = pv;
  __syncthreads();
  if (t == 0) vsh = red[0] + red[1] + bv2[0];
  if (t < N_ACT) {
    float adv = ba2[t];
    for (int j = 0; j < HID; ++j) adv = fmaf(ha[j], Wa2[j * N_ACT + t], adv);
    advs[t] = adv;
  }
  __syncthreads();
  if (t < N_ACT) {
    float m = 0.f;
#pragma unroll
    for (int a = 0; a < N_ACT; ++a) m += advs[a];
    m *= (1.0f / N_ACT);
    out[t] = vsh + advs[t] - m;
  }
}

// ---------------- launch ----------------

extern "C" void kernel_launch(void* const* d_in, const int* in_sizes, int n_in,
                              void* d_out, int out_size, void* d_ws, size_t ws_size,
                              hipStream_t stream) {
  const float* x   = (const float*)d_in[0];
  const int*   ei  = (const int*)d_in[1];
  const float* W1  = (const float*)d_in[2];
  const float* b1  = (const float*)d_in[3];
  const float* W2  = (const float*)d_in[4];
  const float* b2  = (const float*)d_in[5];
  const float* W3  = (const float*)d_in[6];
  const float* b3  = (const float*)d_in[7];
  const float* Wv1 = (const float*)d_in[8];
  const float* bv1 = (const float*)d_in[9];
  const float* Wv2 = (const float*)d_in[10];
  const float* bv2 = (const float*)d_in[11];
  const float* Wa1 = (const float*)d_in[12];
  const float* ba1 = (const float*)d_in[13];
  const float* Wa2 = (const float*)d_in[14];
  const float* ba2 = (const float*)d_in[15];
  float* out = (float*)d_out;

  const int N = in_sizes[0] / F_IN;   // 50000 (< 65535 required: u16 src + dummy N)
  const int E = in_sizes[1] / 2;      // 800000
  const int* esrc = ei;
  const int* edst = ei + E;
  const int nbkt = (N + 255) >> 8;    // 196
  const int gE = (E + EPB - 1) / EPB;

  char* p = (char*)d_ws;
  auto alloc = [&](size_t bytes) {
    void* r = (void*)p;
    p += (bytes + 1023) & ~(size_t)1023;
    return r;
  };
  unsigned* ebuf   = (unsigned*)alloc((size_t)nbkt * CAP * 4);     // padded buckets
  int*   gcur      = (int*)alloc((size_t)nbkt * 4);
  int2*  rbe       = (int2*)alloc((size_t)N * 8);
  float* dinv      = (float*)alloc((size_t)N * 4);
  unsigned short* cs = (unsigned short*)alloc((size_t)nbkt * CAP * 2);
  bf16*  xs        = (bf16*)alloc((size_t)(N + 1) * FP * 2);
  bf16*  WT2       = (bf16*)alloc(128 * 128 * 2);
  bf16*  WT3       = (bf16*)alloc(128 * 128 * 2);
  unsigned* H8a    = (unsigned*)alloc((size_t)(N + 1) * 128);      // h1 fp8 (+zero row)
  unsigned* H8b    = (unsigned*)alloc((size_t)(N + 1) * 128);      // h2 fp8 (+zero row)
  float* gsum      = (float*)alloc(HID * 4);

  // init (cursors, gsum, dummy zero rows at index N)
  k_init<<<1, 256, 0, stream>>>(gcur, gsum, (unsigned*)(xs + (size_t)N * FP),
                                H8a + (size_t)N * 32, H8b + (size_t)N * 32, nbkt);
  k_part<<<gE, 256, 0, stream>>>(esrc, edst, gcur, ebuf, W2, W3, WT2, WT3, E, nbkt);
  k_local<<<nbkt, 1024, 0, stream>>>(ebuf, gcur, rbe, dinv, cs, x, xs, N);

  // layer 1 (fused gather16 + GEMM -> fp8 h1)
  k_layer1<<<(N + 63) / 64, 256, 0, stream>>>(xs, dinv, rbe, cs, W1, b1, H8a, N);

  // layers 2/3: fused fp8 gather + MFMA GEMM (32-node tiles)
  int gL = (N + 31) / 32;
  k_layer<false><<<gL, 512, 0, stream>>>(H8a, dinv, rbe, cs, WT2, b2,
                                         (unsigned char*)H8b, gsum, N);
  k_layer<true><<<gL, 512, 0, stream>>>(H8b, dinv, rbe, cs, WT3, b3,
                                        (unsigned char*)nullptr, gsum, N);

  // head
  k_head<<<1, 128, 0, stream>>>(gsum, Wv1, bv1, Wv2, bv2, Wa1, ba1, Wa2, ba2, out, N);
}